// Round 1
// baseline (8753.226 us; speedup 1.0000x reference)
//
#include <hip/hip_runtime.h>
#include <math.h>

#define NODES 100000
#define EDGES 1600000
#define DH 128
#define DOUT 40

// ---------------- degree (once; dst-only, reused for all 3 layers) ----------------
__global__ void deg_kernel(const int* __restrict__ dst, float* __restrict__ deg) {
    int e = blockIdx.x * blockDim.x + threadIdx.x;
    if (e < EDGES) atomicAdd(&deg[dst[e]], 1.0f);
}

// ---------------- edge-parallel scatter-add: agg[dst] += x[src] ----------------
// 32 threads per edge, each handles 4 contiguous dims (float4 gather + 4 atomics)
__global__ void scatter_kernel(const float* __restrict__ x, const int* __restrict__ src,
                               const int* __restrict__ dst, float* __restrict__ agg) {
    long long t = (long long)blockIdx.x * blockDim.x + threadIdx.x;
    int e = (int)(t >> 5);
    if (e >= EDGES) return;
    int g = ((int)t & 31) * 4;
    int s = src[e], d = dst[e];
    float4 v = *reinterpret_cast<const float4*>(x + (size_t)s * 128 + g);
    float* o = agg + (size_t)d * 128 + g;
    atomicAdd(o + 0, v.x);
    atomicAdd(o + 1, v.y);
    atomicAdd(o + 2, v.z);
    atomicAdd(o + 3, v.w);
}

// ---------------- transpose W[rows][128] -> WT[128][rows] ----------------
__global__ void transpose_kernel(const float* __restrict__ W, float* __restrict__ WT, int rows) {
    int r = blockIdx.x, c = threadIdx.x;
    WT[c * rows + r] = W[r * 128 + c];
}

// ---------------- fused dual GEMM, layers 1/2 (D_out = 128) ----------------
// out[i][j] = sum_k x[i][k]*WsT[k][j] + (agg[i][k]/max(deg,1))*WnT[k][j]
// block = 256 threads, 32 rows per block; LDS tiles stored transposed [k][r].
__global__ __launch_bounds__(256) void gemm12_kernel(
    const float* __restrict__ x, const float* __restrict__ agg, const float* __restrict__ deg,
    const float* __restrict__ WsT, const float* __restrict__ WnT, float* __restrict__ out) {
    __shared__ float xs[128][36];   // pad 36: keeps float4 reads 16B-aligned, spreads write banks
    __shared__ float as[128][36];
    int row0 = blockIdx.x * 32;
    int t = threadIdx.x;
#pragma unroll
    for (int i = 0; i < 4; ++i) {
        int f = t + i * 256;          // float4 index within 32x128 tile
        int r = f >> 5;
        int c4 = (f & 31) * 4;
        float4 xv = *reinterpret_cast<const float4*>(x + (size_t)(row0 + r) * 128 + c4);
        float4 av = *reinterpret_cast<const float4*>(agg + (size_t)(row0 + r) * 128 + c4);
        float rd = 1.0f / fmaxf(deg[row0 + r], 1.0f);
        xs[c4 + 0][r] = xv.x; xs[c4 + 1][r] = xv.y; xs[c4 + 2][r] = xv.z; xs[c4 + 3][r] = xv.w;
        as[c4 + 0][r] = av.x * rd; as[c4 + 1][r] = av.y * rd; as[c4 + 2][r] = av.z * rd; as[c4 + 3][r] = av.w * rd;
    }
    __syncthreads();
    int j0 = (t & 31) * 4;   // 32 col-groups x 4 cols = 128
    int r0 = (t >> 5) * 4;   // 8 row-groups  x 4 rows = 32
    float acc[4][4] = {};
    for (int k = 0; k < 128; ++k) {
        float4 ws4 = *reinterpret_cast<const float4*>(WsT + k * 128 + j0);
        float4 wn4 = *reinterpret_cast<const float4*>(WnT + k * 128 + j0);
        float4 xv = *reinterpret_cast<const float4*>(&xs[k][r0]);
        float4 av = *reinterpret_cast<const float4*>(&as[k][r0]);
        float xr[4] = {xv.x, xv.y, xv.z, xv.w};
        float ar[4] = {av.x, av.y, av.z, av.w};
        float wsv[4] = {ws4.x, ws4.y, ws4.z, ws4.w};
        float wnv[4] = {wn4.x, wn4.y, wn4.z, wn4.w};
#pragma unroll
        for (int ri = 0; ri < 4; ++ri)
#pragma unroll
            for (int jq = 0; jq < 4; ++jq)
                acc[ri][jq] += xr[ri] * wsv[jq] + ar[ri] * wnv[jq];
    }
#pragma unroll
    for (int ri = 0; ri < 4; ++ri) {
        float4 o = make_float4(acc[ri][0], acc[ri][1], acc[ri][2], acc[ri][3]);
        *reinterpret_cast<float4*>(out + (size_t)(row0 + r0 + ri) * 128 + j0) = o;
    }
}

// ---------------- fused dual GEMM, layer 3 (D_out = 40) ----------------
__global__ __launch_bounds__(256) void gemm3_kernel(
    const float* __restrict__ x, const float* __restrict__ agg, const float* __restrict__ deg,
    const float* __restrict__ WsT, const float* __restrict__ WnT, float* __restrict__ out) {
    __shared__ float xs[128][36];
    __shared__ float as[128][36];
    int row0 = blockIdx.x * 32;
    int t = threadIdx.x;
#pragma unroll
    for (int i = 0; i < 4; ++i) {
        int f = t + i * 256;
        int r = f >> 5;
        int c4 = (f & 31) * 4;
        float4 xv = *reinterpret_cast<const float4*>(x + (size_t)(row0 + r) * 128 + c4);
        float4 av = *reinterpret_cast<const float4*>(agg + (size_t)(row0 + r) * 128 + c4);
        float rd = 1.0f / fmaxf(deg[row0 + r], 1.0f);
        xs[c4 + 0][r] = xv.x; xs[c4 + 1][r] = xv.y; xs[c4 + 2][r] = xv.z; xs[c4 + 3][r] = xv.w;
        as[c4 + 0][r] = av.x * rd; as[c4 + 1][r] = av.y * rd; as[c4 + 2][r] = av.z * rd; as[c4 + 3][r] = av.w * rd;
    }
    __syncthreads();
    int j = t & 63;                 // 64 col lanes, only j<40 active for output
    int jc = (j < DOUT) ? j : 0;    // clamp to avoid divergent loads in the loop
    int r0 = (t >> 6) * 8;          // 4 row-groups x 8 rows = 32
    float acc[8] = {};
    for (int k = 0; k < 128; ++k) {
        float wsv = WsT[k * DOUT + jc];
        float wnv = WnT[k * DOUT + jc];
#pragma unroll
        for (int ri = 0; ri < 8; ++ri)
            acc[ri] += xs[k][r0 + ri] * wsv + as[k][r0 + ri] * wnv;
    }
    if (j < DOUT) {
#pragma unroll
        for (int ri = 0; ri < 8; ++ri)
            out[(size_t)(row0 + r0 + ri) * DOUT + j] = acc[ri];
    }
}

// ---------------- batchnorm column stats ----------------
__global__ __launch_bounds__(256) void bn_stats_kernel(const float* __restrict__ h,
                                                       float* __restrict__ sums,
                                                       float* __restrict__ sumsq) {
    int j = threadIdx.x & 127;
    int half = threadIdx.x >> 7;
    float s = 0.f, q = 0.f;
    for (int i = blockIdx.x * 2 + half; i < NODES; i += gridDim.x * 2) {
        float v = h[(size_t)i * 128 + j];
        s += v; q += v * v;
    }
    __shared__ float ls[256], lq[256];
    ls[threadIdx.x] = s; lq[threadIdx.x] = q;
    __syncthreads();
    if (half == 0) {
        atomicAdd(&sums[j], s + ls[threadIdx.x + 128]);
        atomicAdd(&sumsq[j], q + lq[threadIdx.x + 128]);
    }
}

__global__ void bn_finalize_kernel(const float* __restrict__ sums, const float* __restrict__ sumsq,
                                   const float* __restrict__ gamma, const float* __restrict__ beta,
                                   float* __restrict__ a, float* __restrict__ b) {
    int j = threadIdx.x;
    float mean = sums[j] * (1.0f / NODES);
    float var = sumsq[j] * (1.0f / NODES) - mean * mean;
    float rs = rsqrtf(var + 1e-5f);
    float av = gamma[j] * rs;
    a[j] = av;
    b[j] = beta[j] - mean * av;
}

// ---------------- bn apply + relu (in place) ----------------
__global__ void bn_apply_kernel(float* __restrict__ h, const float* __restrict__ a,
                                const float* __restrict__ b) {
    long long t = (long long)blockIdx.x * blockDim.x + threadIdx.x;
    if (t >= (long long)NODES * 32) return;
    int j4 = ((int)(t & 31)) * 4;
    size_t off = (size_t)(t >> 5) * 128 + j4;
    float4 v = *reinterpret_cast<float4*>(h + off);
    float4 a4 = *reinterpret_cast<const float4*>(a + j4);
    float4 b4 = *reinterpret_cast<const float4*>(b + j4);
    v.x = fmaxf(v.x * a4.x + b4.x, 0.f);
    v.y = fmaxf(v.y * a4.y + b4.y, 0.f);
    v.z = fmaxf(v.z * a4.z + b4.z, 0.f);
    v.w = fmaxf(v.w * a4.w + b4.w, 0.f);
    *reinterpret_cast<float4*>(h + off) = v;
}

// ---------------- log_softmax over 40 classes, in place, one wave per row ----------------
__global__ __launch_bounds__(256) void logsoftmax_kernel(float* __restrict__ out) {
    int row = blockIdx.x * 4 + (threadIdx.x >> 6);
    if (row >= NODES) return;
    int lane = threadIdx.x & 63;
    float v = (lane < DOUT) ? out[(size_t)row * DOUT + lane] : -INFINITY;
    float m = v;
    for (int o = 32; o; o >>= 1) m = fmaxf(m, __shfl_xor(m, o, 64));
    float e = (lane < DOUT) ? expf(v - m) : 0.f;
    float s = e;
    for (int o = 32; o; o >>= 1) s += __shfl_xor(s, o, 64);
    if (lane < DOUT) out[(size_t)row * DOUT + lane] = v - m - logf(s);
}

extern "C" void kernel_launch(void* const* d_in, const int* in_sizes, int n_in,
                              void* d_out, int out_size, void* d_ws, size_t ws_size,
                              hipStream_t stream) {
    const float* feat   = (const float*)d_in[0];
    const float* Ws1    = (const float*)d_in[1];
    const float* Wn1    = (const float*)d_in[2];
    const float* gamma1 = (const float*)d_in[3];
    const float* beta1  = (const float*)d_in[4];
    const float* Ws2    = (const float*)d_in[5];
    const float* Wn2    = (const float*)d_in[6];
    const float* gamma2 = (const float*)d_in[7];
    const float* beta2  = (const float*)d_in[8];
    const float* Ws3    = (const float*)d_in[9];
    const float* Wn3    = (const float*)d_in[10];
    const int*   src    = (const int*)d_in[11];
    const int*   dst    = (const int*)d_in[12];
    float* out = (float*)d_out;

    float* ws = (float*)d_ws;
    const size_t NF = (size_t)NODES * 128;
    float* xbuf = ws;                 // N*128
    float* agg  = ws + NF;            // N*128
    float* deg  = ws + 2 * NF;        // N
    float* WsT1 = deg + NODES;        // 128*128
    float* WnT1 = WsT1 + 16384;
    float* WsT2 = WnT1 + 16384;
    float* WnT2 = WsT2 + 16384;
    float* WsT3 = WnT2 + 16384;       // 128*40
    float* WnT3 = WsT3 + 5120;
    float* sums  = WnT3 + 5120;       // 128
    float* sumsq = sums + 128;
    float* avec  = sumsq + 128;
    float* bvec  = avec + 128;

    const int SCAT_GRID = (EDGES * 32) / 256;   // 200000
    const int GEMM_GRID = NODES / 32;           // 3125

    // degree (dst only; shared by all layers)
    hipMemsetAsync(deg, 0, NODES * sizeof(float), stream);
    deg_kernel<<<(EDGES + 255) / 256, 256, 0, stream>>>(dst, deg);

    // weight transposes
    transpose_kernel<<<128, 128, 0, stream>>>(Ws1, WsT1, 128);
    transpose_kernel<<<128, 128, 0, stream>>>(Wn1, WnT1, 128);
    transpose_kernel<<<128, 128, 0, stream>>>(Ws2, WsT2, 128);
    transpose_kernel<<<128, 128, 0, stream>>>(Wn2, WnT2, 128);
    transpose_kernel<<<DOUT, 128, 0, stream>>>(Ws3, WsT3, DOUT);
    transpose_kernel<<<DOUT, 128, 0, stream>>>(Wn3, WnT3, DOUT);

    // ---- layer 1 ----
    hipMemsetAsync(agg, 0, NF * sizeof(float), stream);
    scatter_kernel<<<SCAT_GRID, 256, 0, stream>>>(feat, src, dst, agg);
    gemm12_kernel<<<GEMM_GRID, 256, 0, stream>>>(feat, agg, deg, WsT1, WnT1, xbuf);
    hipMemsetAsync(sums, 0, 2 * 128 * sizeof(float), stream);
    bn_stats_kernel<<<1024, 256, 0, stream>>>(xbuf, sums, sumsq);
    bn_finalize_kernel<<<1, 128, 0, stream>>>(sums, sumsq, gamma1, beta1, avec, bvec);
    bn_apply_kernel<<<(NODES * 32) / 256, 256, 0, stream>>>(xbuf, avec, bvec);

    // ---- layer 2 (GEMM in-place over xbuf: row-local, safe) ----
    hipMemsetAsync(agg, 0, NF * sizeof(float), stream);
    scatter_kernel<<<SCAT_GRID, 256, 0, stream>>>(xbuf, src, dst, agg);
    gemm12_kernel<<<GEMM_GRID, 256, 0, stream>>>(xbuf, agg, deg, WsT2, WnT2, xbuf);
    hipMemsetAsync(sums, 0, 2 * 128 * sizeof(float), stream);
    bn_stats_kernel<<<1024, 256, 0, stream>>>(xbuf, sums, sumsq);
    bn_finalize_kernel<<<1, 128, 0, stream>>>(sums, sumsq, gamma2, beta2, avec, bvec);
    bn_apply_kernel<<<(NODES * 32) / 256, 256, 0, stream>>>(xbuf, avec, bvec);

    // ---- layer 3: logits straight into d_out, then in-place log_softmax ----
    hipMemsetAsync(agg, 0, NF * sizeof(float), stream);
    scatter_kernel<<<SCAT_GRID, 256, 0, stream>>>(xbuf, src, dst, agg);
    gemm3_kernel<<<GEMM_GRID, 256, 0, stream>>>(xbuf, agg, deg, WsT3, WnT3, out);
    logsoftmax_kernel<<<(NODES + 3) / 4, 256, 0, stream>>>(out);
}

// Round 2
// 1289.463 us; speedup vs baseline: 6.7883x; 6.7883x over previous
//
#include <hip/hip_runtime.h>
#include <math.h>

#define NODES 100000
#define EDGES 1600000
#define DH 128
#define DOUT 40

// ---------------- degree histogram (int), once per call ----------------
__global__ void deg_kernel(const int* __restrict__ dst, int* __restrict__ degi) {
    int e = blockIdx.x * blockDim.x + threadIdx.x;
    if (e < EDGES) atomicAdd(&degi[dst[e]], 1);
}

// ---------------- single-block exclusive scan over degi -> rowptr (+cursor copy) ----------------
// 1024 threads, 8 elements/thread per chunk (8192/chunk, 13 chunks).
__global__ __launch_bounds__(1024) void scan_kernel(const int* __restrict__ degi,
                                                    int* __restrict__ rowptr,
                                                    int* __restrict__ cursor) {
    __shared__ int buf[1024];
    __shared__ int carry_s;
    if (threadIdx.x == 0) carry_s = 0;
    __syncthreads();
    for (int base = 0; base < NODES; base += 8192) {
        int idx0 = base + threadIdx.x * 8;
        int loc[8];
        int s = 0;
#pragma unroll
        for (int u = 0; u < 8; ++u) {
            int i = idx0 + u;
            int d = (i < NODES) ? degi[i] : 0;
            loc[u] = s;
            s += d;
        }
        buf[threadIdx.x] = s;
        __syncthreads();
        for (int off = 1; off < 1024; off <<= 1) {
            int t = (threadIdx.x >= off) ? buf[threadIdx.x - off] : 0;
            __syncthreads();
            buf[threadIdx.x] += t;
            __syncthreads();
        }
        int base_ex = carry_s + ((threadIdx.x > 0) ? buf[threadIdx.x - 1] : 0);
#pragma unroll
        for (int u = 0; u < 8; ++u) {
            int i = idx0 + u;
            if (i < NODES) {
                int rp = base_ex + loc[u];
                rowptr[i] = rp;
                cursor[i] = rp;
            }
        }
        __syncthreads();
        if (threadIdx.x == 1023) carry_s += buf[1023];
        __syncthreads();
    }
    if (threadIdx.x == 0) rowptr[NODES] = EDGES;
}

// ---------------- CSR fill: col[slot of dst[e]] = src[e] ----------------
__global__ void fill_kernel(const int* __restrict__ src, const int* __restrict__ dst,
                            int* __restrict__ cursor, int* __restrict__ col) {
    int e = blockIdx.x * blockDim.x + threadIdx.x;
    if (e < EDGES) {
        int p = atomicAdd(&cursor[dst[e]], 1);
        col[p] = src[e];
    }
}

// ---------------- gather-side mean aggregation: one wave per node ----------------
// lane owns 2 dims (float2); each neighbor = one coalesced 512B wave read.
// Writes agg already divided by max(deg,1).
__global__ __launch_bounds__(256) void gather_agg_kernel(const float* __restrict__ x,
                                                         const int* __restrict__ rowptr,
                                                         const int* __restrict__ col,
                                                         float* __restrict__ agg) {
    int node = __builtin_amdgcn_readfirstlane(blockIdx.x * 4 + (threadIdx.x >> 6));
    if (node >= NODES) return;
    int lane = threadIdx.x & 63;
    int p0 = rowptr[node];
    int p1 = rowptr[node + 1];
    float ax = 0.f, ay = 0.f;
    for (int p = p0; p < p1; ++p) {
        int s = __builtin_amdgcn_readfirstlane(col[p]);
        float2 v = *reinterpret_cast<const float2*>(x + (size_t)s * 128 + lane * 2);
        ax += v.x;
        ay += v.y;
    }
    float rd = 1.0f / fmaxf((float)(p1 - p0), 1.0f);
    *reinterpret_cast<float2*>(agg + (size_t)node * 128 + lane * 2) = make_float2(ax * rd, ay * rd);
}

// ---------------- transpose W[rows][128] -> WT[128][rows] ----------------
__global__ void transpose_kernel(const float* __restrict__ W, float* __restrict__ WT, int rows) {
    int r = blockIdx.x, c = threadIdx.x;
    WT[c * rows + r] = W[r * 128 + c];
}

// ---------------- fused dual GEMM, layers 1/2 (D_out = 128) ----------------
// out[i][j] = sum_k x[i][k]*WsT[k][j] + agg[i][k]*WnT[k][j]   (agg pre-averaged)
__global__ __launch_bounds__(256) void gemm12_kernel(
    const float* __restrict__ x, const float* __restrict__ agg,
    const float* __restrict__ WsT, const float* __restrict__ WnT, float* __restrict__ out) {
    __shared__ float xs[128][36];
    __shared__ float as[128][36];
    int row0 = blockIdx.x * 32;
    int t = threadIdx.x;
#pragma unroll
    for (int i = 0; i < 4; ++i) {
        int f = t + i * 256;
        int r = f >> 5;
        int c4 = (f & 31) * 4;
        float4 xv = *reinterpret_cast<const float4*>(x + (size_t)(row0 + r) * 128 + c4);
        float4 av = *reinterpret_cast<const float4*>(agg + (size_t)(row0 + r) * 128 + c4);
        xs[c4 + 0][r] = xv.x; xs[c4 + 1][r] = xv.y; xs[c4 + 2][r] = xv.z; xs[c4 + 3][r] = xv.w;
        as[c4 + 0][r] = av.x; as[c4 + 1][r] = av.y; as[c4 + 2][r] = av.z; as[c4 + 3][r] = av.w;
    }
    __syncthreads();
    int j0 = (t & 31) * 4;
    int r0 = (t >> 5) * 4;
    float acc[4][4] = {};
    for (int k = 0; k < 128; ++k) {
        float4 ws4 = *reinterpret_cast<const float4*>(WsT + k * 128 + j0);
        float4 wn4 = *reinterpret_cast<const float4*>(WnT + k * 128 + j0);
        float4 xv = *reinterpret_cast<const float4*>(&xs[k][r0]);
        float4 av = *reinterpret_cast<const float4*>(&as[k][r0]);
        float xr[4] = {xv.x, xv.y, xv.z, xv.w};
        float ar[4] = {av.x, av.y, av.z, av.w};
        float wsv[4] = {ws4.x, ws4.y, ws4.z, ws4.w};
        float wnv[4] = {wn4.x, wn4.y, wn4.z, wn4.w};
#pragma unroll
        for (int ri = 0; ri < 4; ++ri)
#pragma unroll
            for (int jq = 0; jq < 4; ++jq)
                acc[ri][jq] += xr[ri] * wsv[jq] + ar[ri] * wnv[jq];
    }
#pragma unroll
    for (int ri = 0; ri < 4; ++ri) {
        float4 o = make_float4(acc[ri][0], acc[ri][1], acc[ri][2], acc[ri][3]);
        *reinterpret_cast<float4*>(out + (size_t)(row0 + r0 + ri) * 128 + j0) = o;
    }
}

// ---------------- fused dual GEMM, layer 3 (D_out = 40) ----------------
__global__ __launch_bounds__(256) void gemm3_kernel(
    const float* __restrict__ x, const float* __restrict__ agg,
    const float* __restrict__ WsT, const float* __restrict__ WnT, float* __restrict__ out) {
    __shared__ float xs[128][36];
    __shared__ float as[128][36];
    int row0 = blockIdx.x * 32;
    int t = threadIdx.x;
#pragma unroll
    for (int i = 0; i < 4; ++i) {
        int f = t + i * 256;
        int r = f >> 5;
        int c4 = (f & 31) * 4;
        float4 xv = *reinterpret_cast<const float4*>(x + (size_t)(row0 + r) * 128 + c4);
        float4 av = *reinterpret_cast<const float4*>(agg + (size_t)(row0 + r) * 128 + c4);
        xs[c4 + 0][r] = xv.x; xs[c4 + 1][r] = xv.y; xs[c4 + 2][r] = xv.z; xs[c4 + 3][r] = xv.w;
        as[c4 + 0][r] = av.x; as[c4 + 1][r] = av.y; as[c4 + 2][r] = av.z; as[c4 + 3][r] = av.w;
    }
    __syncthreads();
    int j = t & 63;
    int jc = (j < DOUT) ? j : 0;
    int r0 = (t >> 6) * 8;
    float acc[8] = {};
    for (int k = 0; k < 128; ++k) {
        float wsv = WsT[k * DOUT + jc];
        float wnv = WnT[k * DOUT + jc];
#pragma unroll
        for (int ri = 0; ri < 8; ++ri)
            acc[ri] += xs[k][r0 + ri] * wsv + as[k][r0 + ri] * wnv;
    }
    if (j < DOUT) {
#pragma unroll
        for (int ri = 0; ri < 8; ++ri)
            out[(size_t)(row0 + r0 + ri) * DOUT + j] = acc[ri];
    }
}

// ---------------- batchnorm column stats ----------------
__global__ __launch_bounds__(256) void bn_stats_kernel(const float* __restrict__ h,
                                                       float* __restrict__ sums,
                                                       float* __restrict__ sumsq) {
    int j = threadIdx.x & 127;
    int half = threadIdx.x >> 7;
    float s = 0.f, q = 0.f;
    for (int i = blockIdx.x * 2 + half; i < NODES; i += gridDim.x * 2) {
        float v = h[(size_t)i * 128 + j];
        s += v; q += v * v;
    }
    __shared__ float ls[256], lq[256];
    ls[threadIdx.x] = s; lq[threadIdx.x] = q;
    __syncthreads();
    if (half == 0) {
        atomicAdd(&sums[j], s + ls[threadIdx.x + 128]);
        atomicAdd(&sumsq[j], q + lq[threadIdx.x + 128]);
    }
}

__global__ void bn_finalize_kernel(const float* __restrict__ sums, const float* __restrict__ sumsq,
                                   const float* __restrict__ gamma, const float* __restrict__ beta,
                                   float* __restrict__ a, float* __restrict__ b) {
    int j = threadIdx.x;
    float mean = sums[j] * (1.0f / NODES);
    float var = sumsq[j] * (1.0f / NODES) - mean * mean;
    float rs = rsqrtf(var + 1e-5f);
    float av = gamma[j] * rs;
    a[j] = av;
    b[j] = beta[j] - mean * av;
}

// ---------------- bn apply + relu (in place) ----------------
__global__ void bn_apply_kernel(float* __restrict__ h, const float* __restrict__ a,
                                const float* __restrict__ b) {
    long long t = (long long)blockIdx.x * blockDim.x + threadIdx.x;
    if (t >= (long long)NODES * 32) return;
    int j4 = ((int)(t & 31)) * 4;
    size_t off = (size_t)(t >> 5) * 128 + j4;
    float4 v = *reinterpret_cast<float4*>(h + off);
    float4 a4 = *reinterpret_cast<const float4*>(a + j4);
    float4 b4 = *reinterpret_cast<const float4*>(b + j4);
    v.x = fmaxf(v.x * a4.x + b4.x, 0.f);
    v.y = fmaxf(v.y * a4.y + b4.y, 0.f);
    v.z = fmaxf(v.z * a4.z + b4.z, 0.f);
    v.w = fmaxf(v.w * a4.w + b4.w, 0.f);
    *reinterpret_cast<float4*>(h + off) = v;
}

// ---------------- log_softmax over 40 classes, in place, one wave per row ----------------
__global__ __launch_bounds__(256) void logsoftmax_kernel(float* __restrict__ out) {
    int row = blockIdx.x * 4 + (threadIdx.x >> 6);
    if (row >= NODES) return;
    int lane = threadIdx.x & 63;
    float v = (lane < DOUT) ? out[(size_t)row * DOUT + lane] : -INFINITY;
    float m = v;
    for (int o = 32; o; o >>= 1) m = fmaxf(m, __shfl_xor(m, o, 64));
    float e = (lane < DOUT) ? expf(v - m) : 0.f;
    float s = e;
    for (int o = 32; o; o >>= 1) s += __shfl_xor(s, o, 64);
    if (lane < DOUT) out[(size_t)row * DOUT + lane] = v - m - logf(s);
}

extern "C" void kernel_launch(void* const* d_in, const int* in_sizes, int n_in,
                              void* d_out, int out_size, void* d_ws, size_t ws_size,
                              hipStream_t stream) {
    const float* feat   = (const float*)d_in[0];
    const float* Ws1    = (const float*)d_in[1];
    const float* Wn1    = (const float*)d_in[2];
    const float* gamma1 = (const float*)d_in[3];
    const float* beta1  = (const float*)d_in[4];
    const float* Ws2    = (const float*)d_in[5];
    const float* Wn2    = (const float*)d_in[6];
    const float* gamma2 = (const float*)d_in[7];
    const float* beta2  = (const float*)d_in[8];
    const float* Ws3    = (const float*)d_in[9];
    const float* Wn3    = (const float*)d_in[10];
    const int*   src    = (const int*)d_in[11];
    const int*   dst    = (const int*)d_in[12];
    float* out = (float*)d_out;

    float* ws = (float*)d_ws;
    const size_t NF = (size_t)NODES * 128;
    float* xbuf = ws;                 // N*128
    float* agg  = ws + NF;            // N*128
    float* WsT1 = ws + 2 * NF;        // 128*128
    float* WnT1 = WsT1 + 16384;
    float* WsT2 = WnT1 + 16384;
    float* WnT2 = WsT2 + 16384;
    float* WsT3 = WnT2 + 16384;       // 128*40
    float* WnT3 = WsT3 + 5120;
    float* sums  = WnT3 + 5120;       // 128
    float* sumsq = sums + 128;
    float* avec  = sumsq + 128;
    float* bvec  = avec + 128;
    int* degi   = (int*)(bvec + 128); // N
    int* rowptr = degi + NODES;       // N+1
    int* cursor = rowptr + NODES + 1; // N
    int* col    = cursor + NODES;     // E

    const int GEMM_GRID = NODES / 32;           // 3125
    const int AGG_GRID  = (NODES + 3) / 4;      // 25000

    // ---- CSR build (once per call; reused by all 3 layers) ----
    hipMemsetAsync(degi, 0, NODES * sizeof(int), stream);
    deg_kernel<<<(EDGES + 255) / 256, 256, 0, stream>>>(dst, degi);
    scan_kernel<<<1, 1024, 0, stream>>>(degi, rowptr, cursor);
    fill_kernel<<<(EDGES + 255) / 256, 256, 0, stream>>>(src, dst, cursor, col);

    // weight transposes
    transpose_kernel<<<128, 128, 0, stream>>>(Ws1, WsT1, 128);
    transpose_kernel<<<128, 128, 0, stream>>>(Wn1, WnT1, 128);
    transpose_kernel<<<128, 128, 0, stream>>>(Ws2, WsT2, 128);
    transpose_kernel<<<128, 128, 0, stream>>>(Wn2, WnT2, 128);
    transpose_kernel<<<DOUT, 128, 0, stream>>>(Ws3, WsT3, DOUT);
    transpose_kernel<<<DOUT, 128, 0, stream>>>(Wn3, WnT3, DOUT);

    // ---- layer 1 ----
    gather_agg_kernel<<<AGG_GRID, 256, 0, stream>>>(feat, rowptr, col, agg);
    gemm12_kernel<<<GEMM_GRID, 256, 0, stream>>>(feat, agg, WsT1, WnT1, xbuf);
    hipMemsetAsync(sums, 0, 2 * 128 * sizeof(float), stream);
    bn_stats_kernel<<<1024, 256, 0, stream>>>(xbuf, sums, sumsq);
    bn_finalize_kernel<<<1, 128, 0, stream>>>(sums, sumsq, gamma1, beta1, avec, bvec);
    bn_apply_kernel<<<(NODES * 32) / 256, 256, 0, stream>>>(xbuf, avec, bvec);

    // ---- layer 2 (GEMM in-place over xbuf: row-local, safe) ----
    gather_agg_kernel<<<AGG_GRID, 256, 0, stream>>>(xbuf, rowptr, col, agg);
    gemm12_kernel<<<GEMM_GRID, 256, 0, stream>>>(xbuf, agg, WsT2, WnT2, xbuf);
    hipMemsetAsync(sums, 0, 2 * 128 * sizeof(float), stream);
    bn_stats_kernel<<<1024, 256, 0, stream>>>(xbuf, sums, sumsq);
    bn_finalize_kernel<<<1, 128, 0, stream>>>(sums, sumsq, gamma2, beta2, avec, bvec);
    bn_apply_kernel<<<(NODES * 32) / 256, 256, 0, stream>>>(xbuf, avec, bvec);

    // ---- layer 3: logits straight into d_out, then in-place log_softmax ----
    gather_agg_kernel<<<AGG_GRID, 256, 0, stream>>>(xbuf, rowptr, col, agg);
    gemm3_kernel<<<GEMM_GRID, 256, 0, stream>>>(xbuf, agg, WsT3, WnT3, out);
    logsoftmax_kernel<<<(NODES + 3) / 4, 256, 0, stream>>>(out);
}

// Round 3
// 930.219 us; speedup vs baseline: 9.4099x; 1.3862x over previous
//
#include <hip/hip_runtime.h>
#include <math.h>

#define NODES 100000
#define EDGES 1600000
#define DH 128
#define DOUT 40

typedef __attribute__((ext_vector_type(8))) short bf16x8;
typedef __attribute__((ext_vector_type(4))) float f32x4;

__device__ inline ushort bfh(float f) {           // f32 -> bf16 bits (RNE)
    uint u = __float_as_uint(f);
    return (ushort)((u + 0x7FFFu + ((u >> 16) & 1u)) >> 16);
}
__device__ inline float bff(ushort h) { return __uint_as_float(((uint)h) << 16); }

// ---------------- degree histogram ----------------
__global__ void deg_kernel(const int* __restrict__ dst, int* __restrict__ degi) {
    int e = blockIdx.x * blockDim.x + threadIdx.x;
    if (e < EDGES) atomicAdd(&degi[dst[e]], 1);
}

// ---------------- parallel scan: block reduce -> scan partials -> rescan ----------------
#define SCAN_B 512
#define SCAN_NB ((NODES + SCAN_B - 1) / SCAN_B)   // 196

__global__ __launch_bounds__(512) void scan1_kernel(const int* __restrict__ degi,
                                                    int* __restrict__ partial) {
    __shared__ int buf[512];
    int g = blockIdx.x * 512 + threadIdx.x;
    buf[threadIdx.x] = (g < NODES) ? degi[g] : 0;
    __syncthreads();
    for (int off = 256; off; off >>= 1) {
        if (threadIdx.x < off) buf[threadIdx.x] += buf[threadIdx.x + off];
        __syncthreads();
    }
    if (threadIdx.x == 0) partial[blockIdx.x] = buf[0];
}

__global__ __launch_bounds__(256) void scan2_kernel(const int* __restrict__ partial,
                                                    int* __restrict__ poff,
                                                    int* __restrict__ rowptr) {
    __shared__ int buf[256];
    int v = (threadIdx.x < SCAN_NB) ? partial[threadIdx.x] : 0;
    buf[threadIdx.x] = v;
    __syncthreads();
    for (int off = 1; off < 256; off <<= 1) {
        int t = (threadIdx.x >= off) ? buf[threadIdx.x - off] : 0;
        __syncthreads();
        buf[threadIdx.x] += t;
        __syncthreads();
    }
    if (threadIdx.x < SCAN_NB) poff[threadIdx.x] = buf[threadIdx.x] - v;  // exclusive
    if (threadIdx.x == 0) rowptr[NODES] = EDGES;
}

__global__ __launch_bounds__(512) void scan3_kernel(const int* __restrict__ degi,
                                                    const int* __restrict__ poff,
                                                    int* __restrict__ rowptr,
                                                    int* __restrict__ cursor) {
    __shared__ int buf[512];
    int g = blockIdx.x * 512 + threadIdx.x;
    int v = (g < NODES) ? degi[g] : 0;
    buf[threadIdx.x] = v;
    __syncthreads();
    for (int off = 1; off < 512; off <<= 1) {
        int t = (threadIdx.x >= off) ? buf[threadIdx.x - off] : 0;
        __syncthreads();
        buf[threadIdx.x] += t;
        __syncthreads();
    }
    if (g < NODES) {
        int ex = poff[blockIdx.x] + buf[threadIdx.x] - v;
        rowptr[g] = ex;
        cursor[g] = ex;
    }
}

// ---------------- CSR fill ----------------
__global__ void fill_kernel(const int* __restrict__ src, const int* __restrict__ dst,
                            int* __restrict__ cursor, int* __restrict__ col) {
    int e = blockIdx.x * blockDim.x + threadIdx.x;
    if (e < EDGES) {
        int p = atomicAdd(&cursor[dst[e]], 1);
        col[p] = src[e];
    }
}

// ---------------- weight split: W f32 [n][k] -> Wh,Wl bf16 (native layout) ----------------
__global__ void wsplit_kernel(const float* __restrict__ W, ushort* __restrict__ Wh,
                              ushort* __restrict__ Wl, int nelem) {
    int i = blockIdx.x * blockDim.x + threadIdx.x;
    if (i >= nelem) return;
    float v = W[i];
    ushort h = bfh(v);
    Wh[i] = h;
    Wl[i] = bfh(v - bff(h));
}

// W3 [40][128] -> padded [48][128]
__global__ void wsplit3_kernel(const float* __restrict__ W, ushort* __restrict__ Wh,
                               ushort* __restrict__ Wl) {
    int i = blockIdx.x * blockDim.x + threadIdx.x;   // 48*128 = 6144
    if (i >= 48 * 128) return;
    int n = i >> 7, k = i & 127;
    float v = (n < DOUT) ? W[n * 128 + k] : 0.f;
    ushort h = bfh(v);
    Wh[i] = h;
    Wl[i] = bfh(v - bff(h));
}

// ---------------- f32 activations -> single-bf16 copy (for gather) ----------------
__global__ void f2b_kernel(const float* __restrict__ f, ushort* __restrict__ b) {
    int i = blockIdx.x * blockDim.x + threadIdx.x;   // per float4
    float4 v = *reinterpret_cast<const float4*>(f + (size_t)i * 4);
    ushort4 o;
    o.x = bfh(v.x); o.y = bfh(v.y); o.z = bfh(v.z); o.w = bfh(v.w);
    *reinterpret_cast<ushort4*>(b + (size_t)i * 4) = o;
}

// ---------------- gather-side mean aggregation (bf16 input, f32 output) ----------------
__global__ __launch_bounds__(256) void gather_agg_kernel(const ushort* __restrict__ xb,
                                                         const int* __restrict__ rowptr,
                                                         const int* __restrict__ col,
                                                         float* __restrict__ agg) {
    int node = __builtin_amdgcn_readfirstlane(blockIdx.x * 4 + (threadIdx.x >> 6));
    if (node >= NODES) return;
    int lane = threadIdx.x & 63;
    int p0 = rowptr[node];
    int p1 = rowptr[node + 1];
    float ax = 0.f, ay = 0.f;
    for (int p = p0; p < p1; ++p) {
        int s = __builtin_amdgcn_readfirstlane(col[p]);
        uint v = *reinterpret_cast<const uint*>(xb + (size_t)s * 128 + lane * 2);
        ax += bff((ushort)(v & 0xffff));
        ay += bff((ushort)(v >> 16));
    }
    float rd = 1.0f / fmaxf((float)(p1 - p0), 1.0f);
    *reinterpret_cast<float2*>(agg + (size_t)node * 128 + lane * 2) = make_float2(ax * rd, ay * rd);
}

// ---------------- split helper for staging ----------------
__device__ inline void split4(float4 v, ushort4& h, ushort4& l) {
    h.x = bfh(v.x); h.y = bfh(v.y); h.z = bfh(v.z); h.w = bfh(v.w);
    l.x = bfh(v.x - bff(h.x)); l.y = bfh(v.y - bff(h.y));
    l.z = bfh(v.z - bff(h.z)); l.w = bfh(v.w - bff(h.w));
}

#define MFMA(a, b, c) __builtin_amdgcn_mfma_f32_16x16x32_bf16(a, b, c, 0, 0, 0)

// ---------------- MFMA dual GEMM, layers 1/2 (3x-bf16 split, f32-equivalent) ----------------
// out[i][j] = sum_k x[i][k]*Ws[j][k] + agg[i][k]*Wn[j][k]
// Block: 256 thr (4 waves), M=32, N=128, K=128. Weights in native [n][k] layout.
__global__ __launch_bounds__(256) void gemm12_kernel(
    const float* __restrict__ x, const float* __restrict__ agg,
    const ushort* __restrict__ Wsh, const ushort* __restrict__ Wsl,
    const ushort* __restrict__ Wnh, const ushort* __restrict__ Wnl,
    float* __restrict__ out) {
    __shared__ ushort xh_s[32 * 128], xl_s[32 * 128], ah_s[32 * 128], al_s[32 * 128];
    int t = threadIdx.x;
    int row0 = blockIdx.x * 32;
#pragma unroll
    for (int i = 0; i < 4; ++i) {
        int c = t + i * 256;            // chunk of 4 cols
        int r = c >> 5;
        int c0 = (c & 31) * 4;
        int cs = c0 ^ ((r & 7) << 3);   // XOR swizzle (16B granule)
        float4 xv = *reinterpret_cast<const float4*>(x + (size_t)(row0 + r) * 128 + c0);
        float4 av = *reinterpret_cast<const float4*>(agg + (size_t)(row0 + r) * 128 + c0);
        ushort4 h, l;
        split4(xv, h, l);
        *reinterpret_cast<ushort4*>(&xh_s[r * 128 + cs]) = h;
        *reinterpret_cast<ushort4*>(&xl_s[r * 128 + cs]) = l;
        split4(av, h, l);
        *reinterpret_cast<ushort4*>(&ah_s[r * 128 + cs]) = h;
        *reinterpret_cast<ushort4*>(&al_s[r * 128 + cs]) = l;
    }
    __syncthreads();
    int w = t >> 6;
    int l = t & 63;
    int lr = l & 15;          // A-row / B-col / D-col within tile
    int kq = (l >> 4) * 8;    // k offset within K=32 step
    int n0 = w * 32;
    f32x4 acc[2][2] = {};     // [row-tile][col-tile]
    for (int kk = 0; kk < 4; ++kk) {
        int kf = kk * 32 + kq;
        bf16x8 a_xh[2], a_xl[2], a_ah[2], a_al[2];
#pragma unroll
        for (int rt = 0; rt < 2; ++rt) {
            int r = rt * 16 + lr;
            int ks = kf ^ ((r & 7) << 3);
            a_xh[rt] = *reinterpret_cast<const bf16x8*>(&xh_s[r * 128 + ks]);
            a_xl[rt] = *reinterpret_cast<const bf16x8*>(&xl_s[r * 128 + ks]);
            a_ah[rt] = *reinterpret_cast<const bf16x8*>(&ah_s[r * 128 + ks]);
            a_al[rt] = *reinterpret_cast<const bf16x8*>(&al_s[r * 128 + ks]);
        }
#pragma unroll
        for (int ct = 0; ct < 2; ++ct) {
            size_t wo = (size_t)(n0 + ct * 16 + lr) * 128 + kf;
            bf16x8 bsh = *reinterpret_cast<const bf16x8*>(Wsh + wo);
            bf16x8 bsl = *reinterpret_cast<const bf16x8*>(Wsl + wo);
            bf16x8 bnh = *reinterpret_cast<const bf16x8*>(Wnh + wo);
            bf16x8 bnl = *reinterpret_cast<const bf16x8*>(Wnl + wo);
#pragma unroll
            for (int rt = 0; rt < 2; ++rt) {
                acc[rt][ct] = MFMA(a_xh[rt], bsh, acc[rt][ct]);
                acc[rt][ct] = MFMA(a_xh[rt], bsl, acc[rt][ct]);
                acc[rt][ct] = MFMA(a_xl[rt], bsh, acc[rt][ct]);
                acc[rt][ct] = MFMA(a_ah[rt], bnh, acc[rt][ct]);
                acc[rt][ct] = MFMA(a_ah[rt], bnl, acc[rt][ct]);
                acc[rt][ct] = MFMA(a_al[rt], bnh, acc[rt][ct]);
            }
        }
    }
    int dr = (l >> 4) * 4;
#pragma unroll
    for (int rt = 0; rt < 2; ++rt)
#pragma unroll
        for (int ct = 0; ct < 2; ++ct)
#pragma unroll
            for (int j = 0; j < 4; ++j)
                out[(size_t)(row0 + rt * 16 + dr + j) * 128 + n0 + ct * 16 + lr] = acc[rt][ct][j];
}

// ---------------- MFMA dual GEMM, layer 3 (D_out=40, padded to 48) ----------------
// Block: 256 thr (4 waves), M=64 (wave = one 16-row tile), N=48.
__global__ __launch_bounds__(256) void gemm3_kernel(
    const float* __restrict__ x, const float* __restrict__ agg,
    const ushort* __restrict__ Wsh, const ushort* __restrict__ Wsl,
    const ushort* __restrict__ Wnh, const ushort* __restrict__ Wnl,
    float* __restrict__ out) {
    __shared__ ushort xh_s[64 * 128], xl_s[64 * 128], ah_s[64 * 128], al_s[64 * 128];
    int t = threadIdx.x;
    int row0 = blockIdx.x * 64;
#pragma unroll
    for (int i = 0; i < 8; ++i) {
        int c = t + i * 256;
        int r = c >> 5;
        int c0 = (c & 31) * 4;
        int cs = c0 ^ ((r & 7) << 3);
        int rr = row0 + r; if (rr >= NODES) rr = NODES - 1;
        float4 xv = *reinterpret_cast<const float4*>(x + (size_t)rr * 128 + c0);
        float4 av = *reinterpret_cast<const float4*>(agg + (size_t)rr * 128 + c0);
        ushort4 h, l;
        split4(xv, h, l);
        *reinterpret_cast<ushort4*>(&xh_s[r * 128 + cs]) = h;
        *reinterpret_cast<ushort4*>(&xl_s[r * 128 + cs]) = l;
        split4(av, h, l);
        *reinterpret_cast<ushort4*>(&ah_s[r * 128 + cs]) = h;
        *reinterpret_cast<ushort4*>(&al_s[r * 128 + cs]) = l;
    }
    __syncthreads();
    int w = t >> 6;
    int l = t & 63;
    int lr = l & 15;
    int kq = (l >> 4) * 8;
    f32x4 acc[3] = {};
    for (int kk = 0; kk < 4; ++kk) {
        int kf = kk * 32 + kq;
        int r = w * 16 + lr;
        int ks = kf ^ ((r & 7) << 3);
        bf16x8 a_xh = *reinterpret_cast<const bf16x8*>(&xh_s[r * 128 + ks]);
        bf16x8 a_xl = *reinterpret_cast<const bf16x8*>(&xl_s[r * 128 + ks]);
        bf16x8 a_ah = *reinterpret_cast<const bf16x8*>(&ah_s[r * 128 + ks]);
        bf16x8 a_al = *reinterpret_cast<const bf16x8*>(&al_s[r * 128 + ks]);
#pragma unroll
        for (int ct = 0; ct < 3; ++ct) {
            size_t wo = (size_t)(ct * 16 + lr) * 128 + kf;
            bf16x8 bsh = *reinterpret_cast<const bf16x8*>(Wsh + wo);
            bf16x8 bsl = *reinterpret_cast<const bf16x8*>(Wsl + wo);
            bf16x8 bnh = *reinterpret_cast<const bf16x8*>(Wnh + wo);
            bf16x8 bnl = *reinterpret_cast<const bf16x8*>(Wnl + wo);
            acc[ct] = MFMA(a_xh, bsh, acc[ct]);
            acc[ct] = MFMA(a_xh, bsl, acc[ct]);
            acc[ct] = MFMA(a_xl, bsh, acc[ct]);
            acc[ct] = MFMA(a_ah, bnh, acc[ct]);
            acc[ct] = MFMA(a_ah, bnl, acc[ct]);
            acc[ct] = MFMA(a_al, bnh, acc[ct]);
        }
    }
    int dr = (l >> 4) * 4;
#pragma unroll
    for (int ct = 0; ct < 3; ++ct) {
        int n = ct * 16 + lr;
        if (n < DOUT) {
#pragma unroll
            for (int j = 0; j < 4; ++j) {
                int row = row0 + w * 16 + dr + j;
                if (row < NODES) out[(size_t)row * DOUT + n] = acc[ct][j];
            }
        }
    }
}

// ---------------- batchnorm column stats ----------------
__global__ __launch_bounds__(256) void bn_stats_kernel(const float* __restrict__ h,
                                                       float* __restrict__ sums,
                                                       float* __restrict__ sumsq) {
    int j = threadIdx.x & 127;
    int half = threadIdx.x >> 7;
    float s = 0.f, q = 0.f;
    for (int i = blockIdx.x * 2 + half; i < NODES; i += gridDim.x * 2) {
        float v = h[(size_t)i * 128 + j];
        s += v; q += v * v;
    }
    __shared__ float ls[256], lq[256];
    ls[threadIdx.x] = s; lq[threadIdx.x] = q;
    __syncthreads();
    if (half == 0) {
        atomicAdd(&sums[j], s + ls[threadIdx.x + 128]);
        atomicAdd(&sumsq[j], q + lq[threadIdx.x + 128]);
    }
}

__global__ void bn_finalize_kernel(const float* __restrict__ sums, const float* __restrict__ sumsq,
                                   const float* __restrict__ gamma, const float* __restrict__ beta,
                                   float* __restrict__ a, float* __restrict__ b) {
    int j = threadIdx.x;
    float mean = sums[j] * (1.0f / NODES);
    float var = sumsq[j] * (1.0f / NODES) - mean * mean;
    float rs = rsqrtf(var + 1e-5f);
    float av = gamma[j] * rs;
    a[j] = av;
    b[j] = beta[j] - mean * av;
}

// ---------------- bn apply + relu: writes f32 (for GEMM) and bf16 (for gather) ----------------
__global__ void bn_apply_kernel(float* __restrict__ h, ushort* __restrict__ hb,
                                const float* __restrict__ a, const float* __restrict__ b) {
    long long t = (long long)blockIdx.x * blockDim.x + threadIdx.x;
    if (t >= (long long)NODES * 32) return;
    int j4 = ((int)(t & 31)) * 4;
    size_t off = (size_t)(t >> 5) * 128 + j4;
    float4 v = *reinterpret_cast<float4*>(h + off);
    float4 a4 = *reinterpret_cast<const float4*>(a + j4);
    float4 b4 = *reinterpret_cast<const float4*>(b + j4);
    v.x = fmaxf(v.x * a4.x + b4.x, 0.f);
    v.y = fmaxf(v.y * a4.y + b4.y, 0.f);
    v.z = fmaxf(v.z * a4.z + b4.z, 0.f);
    v.w = fmaxf(v.w * a4.w + b4.w, 0.f);
    *reinterpret_cast<float4*>(h + off) = v;
    ushort4 o;
    o.x = bfh(v.x); o.y = bfh(v.y); o.z = bfh(v.z); o.w = bfh(v.w);
    *reinterpret_cast<ushort4*>(hb + off) = o;
}

// ---------------- log_softmax over 40 classes, in place ----------------
__global__ __launch_bounds__(256) void logsoftmax_kernel(float* __restrict__ out) {
    int row = blockIdx.x * 4 + (threadIdx.x >> 6);
    if (row >= NODES) return;
    int lane = threadIdx.x & 63;
    float v = (lane < DOUT) ? out[(size_t)row * DOUT + lane] : -INFINITY;
    float m = v;
    for (int o = 32; o; o >>= 1) m = fmaxf(m, __shfl_xor(m, o, 64));
    float e = (lane < DOUT) ? expf(v - m) : 0.f;
    float s = e;
    for (int o = 32; o; o >>= 1) s += __shfl_xor(s, o, 64);
    if (lane < DOUT) out[(size_t)row * DOUT + lane] = v - m - logf(s);
}

extern "C" void kernel_launch(void* const* d_in, const int* in_sizes, int n_in,
                              void* d_out, int out_size, void* d_ws, size_t ws_size,
                              hipStream_t stream) {
    const float* feat   = (const float*)d_in[0];
    const float* Ws1    = (const float*)d_in[1];
    const float* Wn1    = (const float*)d_in[2];
    const float* gamma1 = (const float*)d_in[3];
    const float* beta1  = (const float*)d_in[4];
    const float* Ws2    = (const float*)d_in[5];
    const float* Wn2    = (const float*)d_in[6];
    const float* gamma2 = (const float*)d_in[7];
    const float* beta2  = (const float*)d_in[8];
    const float* Ws3    = (const float*)d_in[9];
    const float* Wn3    = (const float*)d_in[10];
    const int*   src    = (const int*)d_in[11];
    const int*   dst    = (const int*)d_in[12];
    float* out = (float*)d_out;

    float* ws = (float*)d_ws;
    const size_t NF = (size_t)NODES * 128;
    float* xbuf = ws;                       // N*128 f32
    float* agg  = ws + NF;                  // N*128 f32
    float* sums  = ws + 2 * NF;             // 128
    float* sumsq = sums + 128;
    float* avec  = sumsq + 128;
    float* bvec  = avec + 128;
    ushort* xb   = (ushort*)(bvec + 128);   // N*128 bf16 (gather input)
    ushort* Wsh1 = xb + NF;                 // 8 x 16384 (layers 1,2)
    ushort* Wsl1 = Wsh1 + 16384;
    ushort* Wnh1 = Wsl1 + 16384;
    ushort* Wnl1 = Wnh1 + 16384;
    ushort* Wsh2 = Wnl1 + 16384;
    ushort* Wsl2 = Wsh2 + 16384;
    ushort* Wnh2 = Wsl2 + 16384;
    ushort* Wnl2 = Wnh2 + 16384;
    ushort* Wsh3 = Wnl2 + 16384;            // 4 x 6144 (padded 48x128)
    ushort* Wsl3 = Wsh3 + 6144;
    ushort* Wnh3 = Wsl3 + 6144;
    ushort* Wnl3 = Wnh3 + 6144;
    int* degi   = (int*)(Wnl3 + 6144);      // N
    int* rowptr = degi + NODES;             // N+1
    int* cursor = rowptr + NODES + 1;       // N
    int* partial= cursor + NODES;           // 256
    int* poff   = partial + 256;            // 256
    int* col    = poff + 256;               // E

    const int GEMM_GRID = NODES / 32;            // 3125
    const int GEMM3_GRID = (NODES + 63) / 64;    // 1563
    const int AGG_GRID  = (NODES + 3) / 4;       // 25000

    // ---- CSR build ----
    hipMemsetAsync(degi, 0, NODES * sizeof(int), stream);
    deg_kernel<<<(EDGES + 255) / 256, 256, 0, stream>>>(dst, degi);
    scan1_kernel<<<SCAN_NB, 512, 0, stream>>>(degi, partial);
    scan2_kernel<<<1, 256, 0, stream>>>(partial, poff, rowptr);
    scan3_kernel<<<SCAN_NB, 512, 0, stream>>>(degi, poff, rowptr, cursor);
    fill_kernel<<<(EDGES + 255) / 256, 256, 0, stream>>>(src, dst, cursor, col);

    // ---- weight hi/lo splits (native [n][k] layout; no transpose) ----
    wsplit_kernel<<<64, 256, 0, stream>>>(Ws1, Wsh1, Wsl1, 16384);
    wsplit_kernel<<<64, 256, 0, stream>>>(Wn1, Wnh1, Wnl1, 16384);
    wsplit_kernel<<<64, 256, 0, stream>>>(Ws2, Wsh2, Wsl2, 16384);
    wsplit_kernel<<<64, 256, 0, stream>>>(Wn2, Wnh2, Wnl2, 16384);
    wsplit3_kernel<<<24, 256, 0, stream>>>(Ws3, Wsh3, Wsl3);
    wsplit3_kernel<<<24, 256, 0, stream>>>(Wn3, Wnh3, Wnl3);

    // ---- feat -> bf16 copy for gather ----
    f2b_kernel<<<(int)(NF / 4 / 256), 256, 0, stream>>>(feat, xb);

    // ---- layer 1 ----
    gather_agg_kernel<<<AGG_GRID, 256, 0, stream>>>(xb, rowptr, col, agg);
    gemm12_kernel<<<GEMM_GRID, 256, 0, stream>>>(feat, agg, Wsh1, Wsl1, Wnh1, Wnl1, xbuf);
    hipMemsetAsync(sums, 0, 2 * 128 * sizeof(float), stream);
    bn_stats_kernel<<<1024, 256, 0, stream>>>(xbuf, sums, sumsq);
    bn_finalize_kernel<<<1, 128, 0, stream>>>(sums, sumsq, gamma1, beta1, avec, bvec);
    bn_apply_kernel<<<(NODES * 32) / 256, 256, 0, stream>>>(xbuf, xb, avec, bvec);

    // ---- layer 2 (GEMM in-place: rows are block-private) ----
    gather_agg_kernel<<<AGG_GRID, 256, 0, stream>>>(xb, rowptr, col, agg);
    gemm12_kernel<<<GEMM_GRID, 256, 0, stream>>>(xbuf, agg, Wsh2, Wsl2, Wnh2, Wnl2, xbuf);
    hipMemsetAsync(sums, 0, 2 * 128 * sizeof(float), stream);
    bn_stats_kernel<<<1024, 256, 0, stream>>>(xbuf, sums, sumsq);
    bn_finalize_kernel<<<1, 128, 0, stream>>>(sums, sumsq, gamma2, beta2, avec, bvec);
    bn_apply_kernel<<<(NODES * 32) / 256, 256, 0, stream>>>(xbuf, xb, avec, bvec);

    // ---- layer 3 ----
    gather_agg_kernel<<<AGG_GRID, 256, 0, stream>>>(xb, rowptr, col, agg);
    gemm3_kernel<<<GEMM3_GRID, 256, 0, stream>>>(xbuf, agg, Wsh3, Wsl3, Wnh3, Wnl3, out);
    logsoftmax_kernel<<<(NODES + 3) / 4, 256, 0, stream>>>(out);
}

// Round 4
// 802.015 us; speedup vs baseline: 10.9140x; 1.1599x over previous
//
#include <hip/hip_runtime.h>
#include <math.h>

#define NODES 100000
#define EDGES 1600000
#define DH 128
#define DOUT 40

// ---- CSR bucket-sort geometry ----
#define BSHIFT 9
#define NBUCK 196                 // ceil(NODES/512); 196*512 = 100352
#define HB 200                    // histogram blocks
#define EPB 8000                  // edges per histogram block (200*8000 = 1.6M)
#define GH (NBUCK * HB)           // 39200 (bucket,block) counts
#define NHS ((GH + 511) / 512)    // 77 scan blocks

typedef __attribute__((ext_vector_type(8))) short bf16x8;
typedef __attribute__((ext_vector_type(4))) float f32x4;

__device__ inline ushort bfh(float f) {           // f32 -> bf16 bits (RNE)
    uint u = __float_as_uint(f);
    return (ushort)((u + 0x7FFFu + ((u >> 16) & 1u)) >> 16);
}
__device__ inline float bff(ushort h) { return __uint_as_float(((uint)h) << 16); }

// ================= CSR build: no global atomics =================

// per-block LDS histogram over coarse buckets (dst>>9)
__global__ __launch_bounds__(256) void hist1_kernel(const int* __restrict__ dst,
                                                    uint* __restrict__ ghist) {
    __shared__ uint h[NBUCK];
    int t = threadIdx.x;
    if (t < NBUCK) h[t] = 0;
    __syncthreads();
    int e0 = blockIdx.x * EPB;
    for (int e = e0 + t; e < e0 + EPB; e += 256)
        atomicAdd(&h[((uint)dst[e]) >> BSHIFT], 1u);
    __syncthreads();
    if (t < NBUCK) ghist[t * HB + blockIdx.x] = h[t];   // bucket-major
}

__global__ __launch_bounds__(512) void hs1_kernel(const uint* __restrict__ ghist,
                                                  uint* __restrict__ hpart) {
    __shared__ uint buf[512];
    int i = blockIdx.x * 512 + threadIdx.x;
    buf[threadIdx.x] = (i < GH) ? ghist[i] : 0;
    __syncthreads();
    for (int off = 256; off; off >>= 1) {
        if (threadIdx.x < off) buf[threadIdx.x] += buf[threadIdx.x + off];
        __syncthreads();
    }
    if (threadIdx.x == 0) hpart[blockIdx.x] = buf[0];
}

__global__ __launch_bounds__(128) void hs2_kernel(const uint* __restrict__ hpart,
                                                  uint* __restrict__ hpoff,
                                                  int* __restrict__ rowptr,
                                                  int* __restrict__ bucket_base) {
    __shared__ uint buf[128];
    uint v = (threadIdx.x < NHS) ? hpart[threadIdx.x] : 0;
    buf[threadIdx.x] = v;
    __syncthreads();
    for (int off = 1; off < 128; off <<= 1) {
        uint tv = (threadIdx.x >= off) ? buf[threadIdx.x - off] : 0;
        __syncthreads();
        buf[threadIdx.x] += tv;
        __syncthreads();
    }
    if (threadIdx.x < NHS) hpoff[threadIdx.x] = buf[threadIdx.x] - v;   // exclusive
    if (threadIdx.x == 0) { rowptr[NODES] = EDGES; bucket_base[NBUCK] = EDGES; }
}

__global__ __launch_bounds__(512) void hs3_kernel(uint* __restrict__ ghist,
                                                  const uint* __restrict__ hpoff,
                                                  int* __restrict__ bucket_base) {
    __shared__ uint buf[512];
    int i = blockIdx.x * 512 + threadIdx.x;
    uint v = (i < GH) ? ghist[i] : 0;
    buf[threadIdx.x] = v;
    __syncthreads();
    for (int off = 1; off < 512; off <<= 1) {
        uint tv = (threadIdx.x >= off) ? buf[threadIdx.x - off] : 0;
        __syncthreads();
        buf[threadIdx.x] += tv;
        __syncthreads();
    }
    if (i < GH) {
        uint ex = hpoff[blockIdx.x] + buf[threadIdx.x] - v;   // global exclusive
        ghist[i] = ex;
        if (i % HB == 0) bucket_base[i / HB] = (int)ex;
    }
}

// bucket-partition edges into ebuf (uint2 = {dst, src}); LDS cursors only
__global__ __launch_bounds__(256) void scatter1_kernel(const int* __restrict__ src,
                                                       const int* __restrict__ dst,
                                                       const uint* __restrict__ ghist,
                                                       uint2* __restrict__ ebuf) {
    __shared__ uint cur[NBUCK];
    int t = threadIdx.x;
    if (t < NBUCK) cur[t] = ghist[t * HB + blockIdx.x];
    __syncthreads();
    int e0 = blockIdx.x * EPB;
    for (int e = e0 + t; e < e0 + EPB; e += 256) {
        uint d = (uint)dst[e];
        uint s = (uint)src[e];
        uint pos = atomicAdd(&cur[d >> BSHIFT], 1u);
        ebuf[pos] = make_uint2(d, s);
    }
}

// per-bucket CSR: LDS hist over 512 nodes -> rowptr; LDS-cursor fill of col
__global__ __launch_bounds__(256) void csr2_kernel(const uint2* __restrict__ ebuf,
                                                   const int* __restrict__ bucket_base,
                                                   int* __restrict__ rowptr,
                                                   int* __restrict__ col) {
    __shared__ uint h[512];
    __shared__ uint cur[512];
    __shared__ uint buf[256];
    int b = blockIdx.x;
    int t = threadIdx.x;
    int seg0 = bucket_base[b];
    int seg1 = bucket_base[b + 1];
    h[t] = 0; h[t + 256] = 0;
    __syncthreads();
    uint nbase = (uint)b << BSHIFT;
    for (int e = seg0 + t; e < seg1; e += 256)
        atomicAdd(&h[ebuf[e].x - nbase], 1u);
    __syncthreads();
    uint s0 = h[2 * t], s1 = h[2 * t + 1];
    uint pair = s0 + s1;
    buf[t] = pair;
    __syncthreads();
    for (int off = 1; off < 256; off <<= 1) {
        uint tv = (t >= off) ? buf[t - off] : 0;
        __syncthreads();
        buf[t] += tv;
        __syncthreads();
    }
    uint epre = buf[t] - pair;            // exclusive pair offset
    cur[2 * t]     = seg0 + epre;
    cur[2 * t + 1] = seg0 + epre + s0;
    int node0 = (int)nbase + 2 * t;
    if (node0 < NODES)     rowptr[node0]     = seg0 + epre;
    if (node0 + 1 < NODES) rowptr[node0 + 1] = seg0 + epre + s0;
    __syncthreads();
    for (int e = seg0 + t; e < seg1; e += 256) {
        uint2 p = ebuf[e];
        uint pos = atomicAdd(&cur[p.x - nbase], 1u);
        col[pos] = (int)p.y;
    }
}

// ================= weights / activations =================

__global__ void wsplit_kernel(const float* __restrict__ W, ushort* __restrict__ Wh,
                              ushort* __restrict__ Wl, int nelem) {
    int i = blockIdx.x * blockDim.x + threadIdx.x;
    if (i >= nelem) return;
    float v = W[i];
    ushort h = bfh(v);
    Wh[i] = h;
    Wl[i] = bfh(v - bff(h));
}

__global__ void wsplit3_kernel(const float* __restrict__ W, ushort* __restrict__ Wh,
                               ushort* __restrict__ Wl) {
    int i = blockIdx.x * blockDim.x + threadIdx.x;   // 48*128 = 6144
    if (i >= 48 * 128) return;
    int n = i >> 7, k = i & 127;
    float v = (n < DOUT) ? W[n * 128 + k] : 0.f;
    ushort h = bfh(v);
    Wh[i] = h;
    Wl[i] = bfh(v - bff(h));
}

__global__ void f2b_kernel(const float* __restrict__ f, ushort* __restrict__ b) {
    int i = blockIdx.x * blockDim.x + threadIdx.x;   // per float4
    float4 v = *reinterpret_cast<const float4*>(f + (size_t)i * 4);
    ushort4 o;
    o.x = bfh(v.x); o.y = bfh(v.y); o.z = bfh(v.z); o.w = bfh(v.w);
    *reinterpret_cast<ushort4*>(b + (size_t)i * 4) = o;
}

// ================= gather-side mean aggregation =================
__global__ __launch_bounds__(256) void gather_agg_kernel(const ushort* __restrict__ xb,
                                                         const int* __restrict__ rowptr,
                                                         const int* __restrict__ col,
                                                         float* __restrict__ agg) {
    int node = __builtin_amdgcn_readfirstlane(blockIdx.x * 4 + (threadIdx.x >> 6));
    if (node >= NODES) return;
    int lane = threadIdx.x & 63;
    int p0 = rowptr[node];
    int p1 = rowptr[node + 1];
    float ax = 0.f, ay = 0.f;
    for (int p = p0; p < p1; ++p) {
        int s = __builtin_amdgcn_readfirstlane(col[p]);
        uint v = *reinterpret_cast<const uint*>(xb + (size_t)s * 128 + lane * 2);
        ax += bff((ushort)(v & 0xffff));
        ay += bff((ushort)(v >> 16));
    }
    float rd = 1.0f / fmaxf((float)(p1 - p0), 1.0f);
    *reinterpret_cast<float2*>(agg + (size_t)node * 128 + lane * 2) = make_float2(ax * rd, ay * rd);
}

// ================= MFMA GEMMs (3x-bf16 split) =================

__device__ inline void split4(float4 v, ushort4& h, ushort4& l) {
    h.x = bfh(v.x); h.y = bfh(v.y); h.z = bfh(v.z); h.w = bfh(v.w);
    l.x = bfh(v.x - bff(h.x)); l.y = bfh(v.y - bff(h.y));
    l.z = bfh(v.z - bff(h.z)); l.w = bfh(v.w - bff(h.w));
}

#define MFMA(a, b, c) __builtin_amdgcn_mfma_f32_16x16x32_bf16(a, b, c, 0, 0, 0)

__global__ __launch_bounds__(256) void gemm12_kernel(
    const float* __restrict__ x, const float* __restrict__ agg,
    const ushort* __restrict__ Wsh, const ushort* __restrict__ Wsl,
    const ushort* __restrict__ Wnh, const ushort* __restrict__ Wnl,
    float* __restrict__ out) {
    __shared__ ushort xh_s[32 * 128], xl_s[32 * 128], ah_s[32 * 128], al_s[32 * 128];
    int t = threadIdx.x;
    int row0 = blockIdx.x * 32;
#pragma unroll
    for (int i = 0; i < 4; ++i) {
        int c = t + i * 256;
        int r = c >> 5;
        int c0 = (c & 31) * 4;
        int cs = c0 ^ ((r & 7) << 3);
        float4 xv = *reinterpret_cast<const float4*>(x + (size_t)(row0 + r) * 128 + c0);
        float4 av = *reinterpret_cast<const float4*>(agg + (size_t)(row0 + r) * 128 + c0);
        ushort4 h, l;
        split4(xv, h, l);
        *reinterpret_cast<ushort4*>(&xh_s[r * 128 + cs]) = h;
        *reinterpret_cast<ushort4*>(&xl_s[r * 128 + cs]) = l;
        split4(av, h, l);
        *reinterpret_cast<ushort4*>(&ah_s[r * 128 + cs]) = h;
        *reinterpret_cast<ushort4*>(&al_s[r * 128 + cs]) = l;
    }
    __syncthreads();
    int w = t >> 6;
    int l = t & 63;
    int lr = l & 15;
    int kq = (l >> 4) * 8;
    int n0 = w * 32;
    f32x4 acc[2][2] = {};
    for (int kk = 0; kk < 4; ++kk) {
        int kf = kk * 32 + kq;
        bf16x8 a_xh[2], a_xl[2], a_ah[2], a_al[2];
#pragma unroll
        for (int rt = 0; rt < 2; ++rt) {
            int r = rt * 16 + lr;
            int ks = kf ^ ((r & 7) << 3);
            a_xh[rt] = *reinterpret_cast<const bf16x8*>(&xh_s[r * 128 + ks]);
            a_xl[rt] = *reinterpret_cast<const bf16x8*>(&xl_s[r * 128 + ks]);
            a_ah[rt] = *reinterpret_cast<const bf16x8*>(&ah_s[r * 128 + ks]);
            a_al[rt] = *reinterpret_cast<const bf16x8*>(&al_s[r * 128 + ks]);
        }
#pragma unroll
        for (int ct = 0; ct < 2; ++ct) {
            size_t wo = (size_t)(n0 + ct * 16 + lr) * 128 + kf;
            bf16x8 bsh = *reinterpret_cast<const bf16x8*>(Wsh + wo);
            bf16x8 bsl = *reinterpret_cast<const bf16x8*>(Wsl + wo);
            bf16x8 bnh = *reinterpret_cast<const bf16x8*>(Wnh + wo);
            bf16x8 bnl = *reinterpret_cast<const bf16x8*>(Wnl + wo);
#pragma unroll
            for (int rt = 0; rt < 2; ++rt) {
                acc[rt][ct] = MFMA(a_xh[rt], bsh, acc[rt][ct]);
                acc[rt][ct] = MFMA(a_xh[rt], bsl, acc[rt][ct]);
                acc[rt][ct] = MFMA(a_xl[rt], bsh, acc[rt][ct]);
                acc[rt][ct] = MFMA(a_ah[rt], bnh, acc[rt][ct]);
                acc[rt][ct] = MFMA(a_ah[rt], bnl, acc[rt][ct]);
                acc[rt][ct] = MFMA(a_al[rt], bnh, acc[rt][ct]);
            }
        }
    }
    int dr = (l >> 4) * 4;
#pragma unroll
    for (int rt = 0; rt < 2; ++rt)
#pragma unroll
        for (int ct = 0; ct < 2; ++ct)
#pragma unroll
            for (int j = 0; j < 4; ++j)
                out[(size_t)(row0 + rt * 16 + dr + j) * 128 + n0 + ct * 16 + lr] = acc[rt][ct][j];
}

__global__ __launch_bounds__(256) void gemm3_kernel(
    const float* __restrict__ x, const float* __restrict__ agg,
    const ushort* __restrict__ Wsh, const ushort* __restrict__ Wsl,
    const ushort* __restrict__ Wnh, const ushort* __restrict__ Wnl,
    float* __restrict__ out) {
    __shared__ ushort xh_s[64 * 128], xl_s[64 * 128], ah_s[64 * 128], al_s[64 * 128];
    int t = threadIdx.x;
    int row0 = blockIdx.x * 64;
#pragma unroll
    for (int i = 0; i < 8; ++i) {
        int c = t + i * 256;
        int r = c >> 5;
        int c0 = (c & 31) * 4;
        int cs = c0 ^ ((r & 7) << 3);
        int rr = row0 + r; if (rr >= NODES) rr = NODES - 1;
        float4 xv = *reinterpret_cast<const float4*>(x + (size_t)rr * 128 + c0);
        float4 av = *reinterpret_cast<const float4*>(agg + (size_t)rr * 128 + c0);
        ushort4 h, l;
        split4(xv, h, l);
        *reinterpret_cast<ushort4*>(&xh_s[r * 128 + cs]) = h;
        *reinterpret_cast<ushort4*>(&xl_s[r * 128 + cs]) = l;
        split4(av, h, l);
        *reinterpret_cast<ushort4*>(&ah_s[r * 128 + cs]) = h;
        *reinterpret_cast<ushort4*>(&al_s[r * 128 + cs]) = l;
    }
    __syncthreads();
    int w = t >> 6;
    int l = t & 63;
    int lr = l & 15;
    int kq = (l >> 4) * 8;
    f32x4 acc[3] = {};
    for (int kk = 0; kk < 4; ++kk) {
        int kf = kk * 32 + kq;
        int r = w * 16 + lr;
        int ks = kf ^ ((r & 7) << 3);
        bf16x8 a_xh = *reinterpret_cast<const bf16x8*>(&xh_s[r * 128 + ks]);
        bf16x8 a_xl = *reinterpret_cast<const bf16x8*>(&xl_s[r * 128 + ks]);
        bf16x8 a_ah = *reinterpret_cast<const bf16x8*>(&ah_s[r * 128 + ks]);
        bf16x8 a_al = *reinterpret_cast<const bf16x8*>(&al_s[r * 128 + ks]);
#pragma unroll
        for (int ct = 0; ct < 3; ++ct) {
            size_t wo = (size_t)(ct * 16 + lr) * 128 + kf;
            bf16x8 bsh = *reinterpret_cast<const bf16x8*>(Wsh + wo);
            bf16x8 bsl = *reinterpret_cast<const bf16x8*>(Wsl + wo);
            bf16x8 bnh = *reinterpret_cast<const bf16x8*>(Wnh + wo);
            bf16x8 bnl = *reinterpret_cast<const bf16x8*>(Wnl + wo);
            acc[ct] = MFMA(a_xh, bsh, acc[ct]);
            acc[ct] = MFMA(a_xh, bsl, acc[ct]);
            acc[ct] = MFMA(a_xl, bsh, acc[ct]);
            acc[ct] = MFMA(a_ah, bnh, acc[ct]);
            acc[ct] = MFMA(a_ah, bnl, acc[ct]);
            acc[ct] = MFMA(a_al, bnh, acc[ct]);
        }
    }
    int dr = (l >> 4) * 4;
#pragma unroll
    for (int ct = 0; ct < 3; ++ct) {
        int n = ct * 16 + lr;
        if (n < DOUT) {
#pragma unroll
            for (int j = 0; j < 4; ++j) {
                int row = row0 + w * 16 + dr + j;
                if (row < NODES) out[(size_t)row * DOUT + n] = acc[ct][j];
            }
        }
    }
}

// ================= batchnorm / softmax =================

__global__ __launch_bounds__(256) void bn_stats_kernel(const float* __restrict__ h,
                                                       float* __restrict__ sums,
                                                       float* __restrict__ sumsq) {
    int j = threadIdx.x & 127;
    int half = threadIdx.x >> 7;
    float s = 0.f, q = 0.f;
    for (int i = blockIdx.x * 2 + half; i < NODES; i += gridDim.x * 2) {
        float v = h[(size_t)i * 128 + j];
        s += v; q += v * v;
    }
    __shared__ float ls[256], lq[256];
    ls[threadIdx.x] = s; lq[threadIdx.x] = q;
    __syncthreads();
    if (half == 0) {
        atomicAdd(&sums[j], s + ls[threadIdx.x + 128]);
        atomicAdd(&sumsq[j], q + lq[threadIdx.x + 128]);
    }
}

__global__ void bn_finalize_kernel(const float* __restrict__ sums, const float* __restrict__ sumsq,
                                   const float* __restrict__ gamma, const float* __restrict__ beta,
                                   float* __restrict__ a, float* __restrict__ b) {
    int j = threadIdx.x;
    float mean = sums[j] * (1.0f / NODES);
    float var = sumsq[j] * (1.0f / NODES) - mean * mean;
    float rs = rsqrtf(var + 1e-5f);
    float av = gamma[j] * rs;
    a[j] = av;
    b[j] = beta[j] - mean * av;
}

__global__ void bn_apply_kernel(float* __restrict__ h, ushort* __restrict__ hb,
                                const float* __restrict__ a, const float* __restrict__ b) {
    long long t = (long long)blockIdx.x * blockDim.x + threadIdx.x;
    if (t >= (long long)NODES * 32) return;
    int j4 = ((int)(t & 31)) * 4;
    size_t off = (size_t)(t >> 5) * 128 + j4;
    float4 v = *reinterpret_cast<float4*>(h + off);
    float4 a4 = *reinterpret_cast<const float4*>(a + j4);
    float4 b4 = *reinterpret_cast<const float4*>(b + j4);
    v.x = fmaxf(v.x * a4.x + b4.x, 0.f);
    v.y = fmaxf(v.y * a4.y + b4.y, 0.f);
    v.z = fmaxf(v.z * a4.z + b4.z, 0.f);
    v.w = fmaxf(v.w * a4.w + b4.w, 0.f);
    *reinterpret_cast<float4*>(h + off) = v;
    ushort4 o;
    o.x = bfh(v.x); o.y = bfh(v.y); o.z = bfh(v.z); o.w = bfh(v.w);
    *reinterpret_cast<ushort4*>(hb + off) = o;
}

__global__ __launch_bounds__(256) void logsoftmax_kernel(float* __restrict__ out) {
    int row = blockIdx.x * 4 + (threadIdx.x >> 6);
    if (row >= NODES) return;
    int lane = threadIdx.x & 63;
    float v = (lane < DOUT) ? out[(size_t)row * DOUT + lane] : -INFINITY;
    float m = v;
    for (int o = 32; o; o >>= 1) m = fmaxf(m, __shfl_xor(m, o, 64));
    float e = (lane < DOUT) ? expf(v - m) : 0.f;
    float s = e;
    for (int o = 32; o; o >>= 1) s += __shfl_xor(s, o, 64);
    if (lane < DOUT) out[(size_t)row * DOUT + lane] = v - m - logf(s);
}

extern "C" void kernel_launch(void* const* d_in, const int* in_sizes, int n_in,
                              void* d_out, int out_size, void* d_ws, size_t ws_size,
                              hipStream_t stream) {
    const float* feat   = (const float*)d_in[0];
    const float* Ws1    = (const float*)d_in[1];
    const float* Wn1    = (const float*)d_in[2];
    const float* gamma1 = (const float*)d_in[3];
    const float* beta1  = (const float*)d_in[4];
    const float* Ws2    = (const float*)d_in[5];
    const float* Wn2    = (const float*)d_in[6];
    const float* gamma2 = (const float*)d_in[7];
    const float* beta2  = (const float*)d_in[8];
    const float* Ws3    = (const float*)d_in[9];
    const float* Wn3    = (const float*)d_in[10];
    const int*   src    = (const int*)d_in[11];
    const int*   dst    = (const int*)d_in[12];
    float* out = (float*)d_out;

    float* ws = (float*)d_ws;
    const size_t NF = (size_t)NODES * 128;
    float* xbuf = ws;                       // N*128 f32
    float* agg  = ws + NF;                  // N*128 f32 (aliased as ebuf during CSR build)
    float* sums  = ws + 2 * NF;             // 128
    float* sumsq = sums + 128;
    float* avec  = sumsq + 128;
    float* bvec  = avec + 128;
    ushort* xb   = (ushort*)(bvec + 128);   // N*128 bf16 (gather input)
    ushort* Wsh1 = xb + NF;
    ushort* Wsl1 = Wsh1 + 16384;
    ushort* Wnh1 = Wsl1 + 16384;
    ushort* Wnl1 = Wnh1 + 16384;
    ushort* Wsh2 = Wnl1 + 16384;
    ushort* Wsl2 = Wsh2 + 16384;
    ushort* Wnh2 = Wsl2 + 16384;
    ushort* Wnl2 = Wnh2 + 16384;
    ushort* Wsh3 = Wnl2 + 16384;            // padded 48x128
    ushort* Wsl3 = Wsh3 + 6144;
    ushort* Wnh3 = Wsl3 + 6144;
    ushort* Wnl3 = Wnh3 + 6144;
    int* rowptr = (int*)(Wnl3 + 6144);      // N+1
    uint* ghist = (uint*)(rowptr + NODES + 1);  // GH
    uint* hpart = ghist + GH;               // 128
    uint* hpoff = hpart + 128;              // 128
    int* bucket_base = (int*)(hpoff + 128); // NBUCK+1
    int* col    = bucket_base + NBUCK + 1;  // E
    uint2* ebuf = (uint2*)agg;              // E uint2 (12.8 MB <= 51.2 MB), dead before gather

    const int GEMM_GRID  = NODES / 32;           // 3125
    const int GEMM3_GRID = (NODES + 63) / 64;    // 1563
    const int AGG_GRID   = (NODES + 3) / 4;      // 25000

    // ---- CSR build: bucket sort, LDS atomics only ----
    hist1_kernel<<<HB, 256, 0, stream>>>(dst, ghist);
    hs1_kernel<<<NHS, 512, 0, stream>>>(ghist, hpart);
    hs2_kernel<<<1, 128, 0, stream>>>(hpart, hpoff, rowptr, bucket_base);
    hs3_kernel<<<NHS, 512, 0, stream>>>(ghist, hpoff, bucket_base);
    scatter1_kernel<<<HB, 256, 0, stream>>>(src, dst, ghist, ebuf);
    csr2_kernel<<<NBUCK, 256, 0, stream>>>(ebuf, bucket_base, rowptr, col);

    // ---- weight hi/lo splits ----
    wsplit_kernel<<<64, 256, 0, stream>>>(Ws1, Wsh1, Wsl1, 16384);
    wsplit_kernel<<<64, 256, 0, stream>>>(Wn1, Wnh1, Wnl1, 16384);
    wsplit_kernel<<<64, 256, 0, stream>>>(Ws2, Wsh2, Wsl2, 16384);
    wsplit_kernel<<<64, 256, 0, stream>>>(Wn2, Wnh2, Wnl2, 16384);
    wsplit3_kernel<<<24, 256, 0, stream>>>(Ws3, Wsh3, Wsl3);
    wsplit3_kernel<<<24, 256, 0, stream>>>(Wn3, Wnh3, Wnl3);

    // ---- feat -> bf16 copy for gather ----
    f2b_kernel<<<(int)(NF / 4 / 256), 256, 0, stream>>>(feat, xb);

    // ---- layer 1 ----
    gather_agg_kernel<<<AGG_GRID, 256, 0, stream>>>(xb, rowptr, col, agg);
    gemm12_kernel<<<GEMM_GRID, 256, 0, stream>>>(feat, agg, Wsh1, Wsl1, Wnh1, Wnl1, xbuf);
    hipMemsetAsync(sums, 0, 2 * 128 * sizeof(float), stream);
    bn_stats_kernel<<<1024, 256, 0, stream>>>(xbuf, sums, sumsq);
    bn_finalize_kernel<<<1, 128, 0, stream>>>(sums, sumsq, gamma1, beta1, avec, bvec);
    bn_apply_kernel<<<(NODES * 32) / 256, 256, 0, stream>>>(xbuf, xb, avec, bvec);

    // ---- layer 2 ----
    gather_agg_kernel<<<AGG_GRID, 256, 0, stream>>>(xb, rowptr, col, agg);
    gemm12_kernel<<<GEMM_GRID, 256, 0, stream>>>(xbuf, agg, Wsh2, Wsl2, Wnh2, Wnl2, xbuf);
    hipMemsetAsync(sums, 0, 2 * 128 * sizeof(float), stream);
    bn_stats_kernel<<<1024, 256, 0, stream>>>(xbuf, sums, sumsq);
    bn_finalize_kernel<<<1, 128, 0, stream>>>(sums, sumsq, gamma2, beta2, avec, bvec);
    bn_apply_kernel<<<(NODES * 32) / 256, 256, 0, stream>>>(xbuf, xb, avec, bvec);

    // ---- layer 3 ----
    gather_agg_kernel<<<AGG_GRID, 256, 0, stream>>>(xb, rowptr, col, agg);
    gemm3_kernel<<<GEMM3_GRID, 256, 0, stream>>>(xbuf, agg, Wsh3, Wsl3, Wnh3, Wnl3, out);
    logsoftmax_kernel<<<(NODES + 3) / 4, 256, 0, stream>>>(out);
}

// Round 5
// 678.847 us; speedup vs baseline: 12.8943x; 1.1814x over previous
//
#include <hip/hip_runtime.h>
#include <math.h>

#define NODES 100000
#define EDGES 1600000
#define DH 128
#define DOUT 40

// ---- CSR bucket-sort geometry ----
#define BSHIFT 9
#define NBUCK 196                 // ceil(NODES/512)
#define HB 200                    // histogram blocks
#define EPB 8000                  // edges per histogram block
#define GH (NBUCK * HB)           // 39200
#define NHS ((GH + 511) / 512)    // 77

typedef __attribute__((ext_vector_type(8))) short bf16x8;
typedef __attribute__((ext_vector_type(4))) float f32x4;

__device__ inline ushort bfh(float f) {           // f32 -> bf16 bits (RNE)
    uint u = __float_as_uint(f);
    return (ushort)((u + 0x7FFFu + ((u >> 16) & 1u)) >> 16);
}
__device__ inline float bff(ushort h) { return __uint_as_float(((uint)h) << 16); }

// ================= CSR build: no global atomics =================

__global__ __launch_bounds__(256) void hist1_kernel(const int* __restrict__ dst,
                                                    uint* __restrict__ ghist) {
    __shared__ uint h[NBUCK];
    int t = threadIdx.x;
    if (t < NBUCK) h[t] = 0;
    __syncthreads();
    int e0 = blockIdx.x * EPB;
    for (int e = e0 + t; e < e0 + EPB; e += 256)
        atomicAdd(&h[((uint)dst[e]) >> BSHIFT], 1u);
    __syncthreads();
    if (t < NBUCK) ghist[t * HB + blockIdx.x] = h[t];   // bucket-major
}

__global__ __launch_bounds__(512) void hs1_kernel(const uint* __restrict__ ghist,
                                                  uint* __restrict__ hpart) {
    __shared__ uint buf[512];
    int i = blockIdx.x * 512 + threadIdx.x;
    buf[threadIdx.x] = (i < GH) ? ghist[i] : 0;
    __syncthreads();
    for (int off = 256; off; off >>= 1) {
        if (threadIdx.x < off) buf[threadIdx.x] += buf[threadIdx.x + off];
        __syncthreads();
    }
    if (threadIdx.x == 0) hpart[blockIdx.x] = buf[0];
}

__global__ __launch_bounds__(128) void hs2_kernel(const uint* __restrict__ hpart,
                                                  uint* __restrict__ hpoff,
                                                  int* __restrict__ rowptr,
                                                  int* __restrict__ bucket_base) {
    __shared__ uint buf[128];
    uint v = (threadIdx.x < NHS) ? hpart[threadIdx.x] : 0;
    buf[threadIdx.x] = v;
    __syncthreads();
    for (int off = 1; off < 128; off <<= 1) {
        uint tv = (threadIdx.x >= off) ? buf[threadIdx.x - off] : 0;
        __syncthreads();
        buf[threadIdx.x] += tv;
        __syncthreads();
    }
    if (threadIdx.x < NHS) hpoff[threadIdx.x] = buf[threadIdx.x] - v;   // exclusive
    if (threadIdx.x == 0) { rowptr[NODES] = EDGES; bucket_base[NBUCK] = EDGES; }
}

__global__ __launch_bounds__(512) void hs3_kernel(uint* __restrict__ ghist,
                                                  const uint* __restrict__ hpoff,
                                                  int* __restrict__ bucket_base) {
    __shared__ uint buf[512];
    int i = blockIdx.x * 512 + threadIdx.x;
    uint v = (i < GH) ? ghist[i] : 0;
    buf[threadIdx.x] = v;
    __syncthreads();
    for (int off = 1; off < 512; off <<= 1) {
        uint tv = (threadIdx.x >= off) ? buf[threadIdx.x - off] : 0;
        __syncthreads();
        buf[threadIdx.x] += tv;
        __syncthreads();
    }
    if (i < GH) {
        uint ex = hpoff[blockIdx.x] + buf[threadIdx.x] - v;
        ghist[i] = ex;
        if (i % HB == 0) bucket_base[i / HB] = (int)ex;
    }
}

__global__ __launch_bounds__(256) void scatter1_kernel(const int* __restrict__ src,
                                                       const int* __restrict__ dst,
                                                       const uint* __restrict__ ghist,
                                                       uint2* __restrict__ ebuf) {
    __shared__ uint cur[NBUCK];
    int t = threadIdx.x;
    if (t < NBUCK) cur[t] = ghist[t * HB + blockIdx.x];
    __syncthreads();
    int e0 = blockIdx.x * EPB;
    for (int e = e0 + t; e < e0 + EPB; e += 256) {
        uint d = (uint)dst[e];
        uint s = (uint)src[e];
        uint pos = atomicAdd(&cur[d >> BSHIFT], 1u);
        ebuf[pos] = make_uint2(d, s);
    }
}

__global__ __launch_bounds__(256) void csr2_kernel(const uint2* __restrict__ ebuf,
                                                   const int* __restrict__ bucket_base,
                                                   int* __restrict__ rowptr,
                                                   int* __restrict__ col) {
    __shared__ uint h[512];
    __shared__ uint cur[512];
    __shared__ uint buf[256];
    int b = blockIdx.x;
    int t = threadIdx.x;
    int seg0 = bucket_base[b];
    int seg1 = bucket_base[b + 1];
    h[t] = 0; h[t + 256] = 0;
    __syncthreads();
    uint nbase = (uint)b << BSHIFT;
    for (int e = seg0 + t; e < seg1; e += 256)
        atomicAdd(&h[ebuf[e].x - nbase], 1u);
    __syncthreads();
    uint s0 = h[2 * t], s1 = h[2 * t + 1];
    uint pair = s0 + s1;
    buf[t] = pair;
    __syncthreads();
    for (int off = 1; off < 256; off <<= 1) {
        uint tv = (t >= off) ? buf[t - off] : 0;
        __syncthreads();
        buf[t] += tv;
        __syncthreads();
    }
    uint epre = buf[t] - pair;
    cur[2 * t]     = seg0 + epre;
    cur[2 * t + 1] = seg0 + epre + s0;
    int node0 = (int)nbase + 2 * t;
    if (node0 < NODES)     rowptr[node0]     = seg0 + epre;
    if (node0 + 1 < NODES) rowptr[node0 + 1] = seg0 + epre + s0;
    __syncthreads();
    for (int e = seg0 + t; e < seg1; e += 256) {
        uint2 p = ebuf[e];
        uint pos = atomicAdd(&cur[p.x - nbase], 1u);
        col[pos] = (int)p.y;
    }
}

// ================= combined weight split (all 6 matrices, one dispatch) =================
// layout order: Ws1,Wn1,Ws2,Wn2 (16384 each), then Ws3,Wn3 (padded 48x128 = 6144 each)
__global__ void wsplit_all_kernel(const float* __restrict__ Ws1, const float* __restrict__ Wn1,
                                  const float* __restrict__ Ws2, const float* __restrict__ Wn2,
                                  const float* __restrict__ Ws3, const float* __restrict__ Wn3,
                                  ushort* __restrict__ Wh, ushort* __restrict__ Wl) {
    int i = blockIdx.x * blockDim.x + threadIdx.x;   // 0 .. 77823
    if (i >= 4 * 16384 + 2 * 6144) return;
    float v;
    if (i < 65536) {
        int which = i >> 14, j = i & 16383;
        const float* W = (which == 0) ? Ws1 : (which == 1) ? Wn1 : (which == 2) ? Ws2 : Wn2;
        v = W[j];
    } else {
        int i2 = i - 65536;
        int which = (i2 >= 6144) ? 1 : 0;
        int j = i2 - which * 6144;
        int n = j >> 7, k = j & 127;
        const float* W = which ? Wn3 : Ws3;
        v = (n < DOUT) ? W[n * 128 + k] : 0.f;
    }
    ushort h = bfh(v);
    Wh[i] = h;
    Wl[i] = bfh(v - bff(h));
}

__global__ void f2b_kernel(const float* __restrict__ f, ushort* __restrict__ b) {
    int i = blockIdx.x * blockDim.x + threadIdx.x;   // per float4
    float4 v = *reinterpret_cast<const float4*>(f + (size_t)i * 4);
    ushort4 o;
    o.x = bfh(v.x); o.y = bfh(v.y); o.z = bfh(v.z); o.w = bfh(v.w);
    *reinterpret_cast<ushort4*>(b + (size_t)i * 4) = o;
}

// ================= gather-side mean aggregation: 4 neighbors/wave-iter =================
// 16 lanes per neighbor, each lane loads 16B (8 bf16 dims). 4x MLP vs 1-neighbor/iter.
__global__ __launch_bounds__(256) void gather_agg_kernel(const ushort* __restrict__ xb,
                                                         const int* __restrict__ rowptr,
                                                         const int* __restrict__ col,
                                                         float* __restrict__ agg) {
    int node = blockIdx.x * 4 + (threadIdx.x >> 6);
    int lane = threadIdx.x & 63;
    int g = lane >> 4;        // neighbor sub-group 0..3
    int sub = lane & 15;      // dim chunk: dims [sub*8, sub*8+8)
    int p0 = rowptr[node], p1 = rowptr[node + 1];
    float acc[8] = {};
    for (int p = p0 + g; p < p1; p += 4) {
        int s = col[p];       // 4 consecutive ints across the wave = one 16B line
        uint4 v = *reinterpret_cast<const uint4*>(xb + (size_t)s * 128 + sub * 8);
        acc[0] += bff((ushort)(v.x & 0xffff)); acc[1] += bff((ushort)(v.x >> 16));
        acc[2] += bff((ushort)(v.y & 0xffff)); acc[3] += bff((ushort)(v.y >> 16));
        acc[4] += bff((ushort)(v.z & 0xffff)); acc[5] += bff((ushort)(v.z >> 16));
        acc[6] += bff((ushort)(v.w & 0xffff)); acc[7] += bff((ushort)(v.w >> 16));
    }
#pragma unroll
    for (int j = 0; j < 8; ++j) {
        acc[j] += __shfl_xor(acc[j], 16, 64);
        acc[j] += __shfl_xor(acc[j], 32, 64);
    }
    if (lane < 16) {
        float rd = 1.0f / fmaxf((float)(p1 - p0), 1.0f);
        float4 o0 = make_float4(acc[0] * rd, acc[1] * rd, acc[2] * rd, acc[3] * rd);
        float4 o1 = make_float4(acc[4] * rd, acc[5] * rd, acc[6] * rd, acc[7] * rd);
        *reinterpret_cast<float4*>(agg + (size_t)node * 128 + sub * 8) = o0;
        *reinterpret_cast<float4*>(agg + (size_t)node * 128 + sub * 8 + 4) = o1;
    }
}

// ================= MFMA GEMMs (3x-bf16 split) =================

__device__ inline void split4(float4 v, ushort4& h, ushort4& l) {
    h.x = bfh(v.x); h.y = bfh(v.y); h.z = bfh(v.z); h.w = bfh(v.w);
    l.x = bfh(v.x - bff(h.x)); l.y = bfh(v.y - bff(h.y));
    l.z = bfh(v.z - bff(h.z)); l.w = bfh(v.w - bff(h.w));
}

#define MFMA(a, b, c) __builtin_amdgcn_mfma_f32_16x16x32_bf16(a, b, c, 0, 0, 0)

// also zeroes the BN stat accumulators (block 0) so no separate memset dispatch is needed;
// bn_stats runs strictly after this kernel completes.
__global__ __launch_bounds__(256) void gemm12_kernel(
    const float* __restrict__ x, const float* __restrict__ agg,
    const ushort* __restrict__ Wsh, const ushort* __restrict__ Wsl,
    const ushort* __restrict__ Wnh, const ushort* __restrict__ Wnl,
    float* __restrict__ out, float* __restrict__ stat0) {
    if (blockIdx.x == 0) stat0[threadIdx.x] = 0.f;   // sums[128] ++ sumsq[128]
    __shared__ ushort xh_s[32 * 128], xl_s[32 * 128], ah_s[32 * 128], al_s[32 * 128];
    int t = threadIdx.x;
    int row0 = blockIdx.x * 32;
#pragma unroll
    for (int i = 0; i < 4; ++i) {
        int c = t + i * 256;
        int r = c >> 5;
        int c0 = (c & 31) * 4;
        int cs = c0 ^ ((r & 7) << 3);
        float4 xv = *reinterpret_cast<const float4*>(x + (size_t)(row0 + r) * 128 + c0);
        float4 av = *reinterpret_cast<const float4*>(agg + (size_t)(row0 + r) * 128 + c0);
        ushort4 h, l;
        split4(xv, h, l);
        *reinterpret_cast<ushort4*>(&xh_s[r * 128 + cs]) = h;
        *reinterpret_cast<ushort4*>(&xl_s[r * 128 + cs]) = l;
        split4(av, h, l);
        *reinterpret_cast<ushort4*>(&ah_s[r * 128 + cs]) = h;
        *reinterpret_cast<ushort4*>(&al_s[r * 128 + cs]) = l;
    }
    __syncthreads();
    int w = t >> 6;
    int l = t & 63;
    int lr = l & 15;
    int kq = (l >> 4) * 8;
    int n0 = w * 32;
    f32x4 acc[2][2] = {};
    for (int kk = 0; kk < 4; ++kk) {
        int kf = kk * 32 + kq;
        bf16x8 a_xh[2], a_xl[2], a_ah[2], a_al[2];
#pragma unroll
        for (int rt = 0; rt < 2; ++rt) {
            int r = rt * 16 + lr;
            int ks = kf ^ ((r & 7) << 3);
            a_xh[rt] = *reinterpret_cast<const bf16x8*>(&xh_s[r * 128 + ks]);
            a_xl[rt] = *reinterpret_cast<const bf16x8*>(&xl_s[r * 128 + ks]);
            a_ah[rt] = *reinterpret_cast<const bf16x8*>(&ah_s[r * 128 + ks]);
            a_al[rt] = *reinterpret_cast<const bf16x8*>(&al_s[r * 128 + ks]);
        }
#pragma unroll
        for (int ct = 0; ct < 2; ++ct) {
            size_t wo = (size_t)(n0 + ct * 16 + lr) * 128 + kf;
            bf16x8 bsh = *reinterpret_cast<const bf16x8*>(Wsh + wo);
            bf16x8 bsl = *reinterpret_cast<const bf16x8*>(Wsl + wo);
            bf16x8 bnh = *reinterpret_cast<const bf16x8*>(Wnh + wo);
            bf16x8 bnl = *reinterpret_cast<const bf16x8*>(Wnl + wo);
#pragma unroll
            for (int rt = 0; rt < 2; ++rt) {
                acc[rt][ct] = MFMA(a_xh[rt], bsh, acc[rt][ct]);
                acc[rt][ct] = MFMA(a_xh[rt], bsl, acc[rt][ct]);
                acc[rt][ct] = MFMA(a_xl[rt], bsh, acc[rt][ct]);
                acc[rt][ct] = MFMA(a_ah[rt], bnh, acc[rt][ct]);
                acc[rt][ct] = MFMA(a_ah[rt], bnl, acc[rt][ct]);
                acc[rt][ct] = MFMA(a_al[rt], bnh, acc[rt][ct]);
            }
        }
    }
    int dr = (l >> 4) * 4;
#pragma unroll
    for (int rt = 0; rt < 2; ++rt)
#pragma unroll
        for (int ct = 0; ct < 2; ++ct)
#pragma unroll
            for (int j = 0; j < 4; ++j)
                out[(size_t)(row0 + rt * 16 + dr + j) * 128 + n0 + ct * 16 + lr] = acc[rt][ct][j];
}

// layer 3 + fused log-softmax (row's 48 cols live in 16 lanes x 3 regs -> width-16 LSE)
__global__ __launch_bounds__(256) void gemm3_kernel(
    const float* __restrict__ x, const float* __restrict__ agg,
    const ushort* __restrict__ Wsh, const ushort* __restrict__ Wsl,
    const ushort* __restrict__ Wnh, const ushort* __restrict__ Wnl,
    float* __restrict__ out) {
    __shared__ ushort xh_s[64 * 128], xl_s[64 * 128], ah_s[64 * 128], al_s[64 * 128];
    int t = threadIdx.x;
    int row0 = blockIdx.x * 64;
#pragma unroll
    for (int i = 0; i < 8; ++i) {
        int c = t + i * 256;
        int r = c >> 5;
        int c0 = (c & 31) * 4;
        int cs = c0 ^ ((r & 7) << 3);
        int rr = row0 + r; if (rr >= NODES) rr = NODES - 1;
        float4 xv = *reinterpret_cast<const float4*>(x + (size_t)rr * 128 + c0);
        float4 av = *reinterpret_cast<const float4*>(agg + (size_t)rr * 128 + c0);
        ushort4 h, l;
        split4(xv, h, l);
        *reinterpret_cast<ushort4*>(&xh_s[r * 128 + cs]) = h;
        *reinterpret_cast<ushort4*>(&xl_s[r * 128 + cs]) = l;
        split4(av, h, l);
        *reinterpret_cast<ushort4*>(&ah_s[r * 128 + cs]) = h;
        *reinterpret_cast<ushort4*>(&al_s[r * 128 + cs]) = l;
    }
    __syncthreads();
    int w = t >> 6;
    int l = t & 63;
    int lr = l & 15;
    int kq = (l >> 4) * 8;
    f32x4 acc[3] = {};
    for (int kk = 0; kk < 4; ++kk) {
        int kf = kk * 32 + kq;
        int r = w * 16 + lr;
        int ks = kf ^ ((r & 7) << 3);
        bf16x8 a_xh = *reinterpret_cast<const bf16x8*>(&xh_s[r * 128 + ks]);
        bf16x8 a_xl = *reinterpret_cast<const bf16x8*>(&xl_s[r * 128 + ks]);
        bf16x8 a_ah = *reinterpret_cast<const bf16x8*>(&ah_s[r * 128 + ks]);
        bf16x8 a_al = *reinterpret_cast<const bf16x8*>(&al_s[r * 128 + ks]);
#pragma unroll
        for (int ct = 0; ct < 3; ++ct) {
            size_t wo = (size_t)(ct * 16 + lr) * 128 + kf;
            bf16x8 bsh = *reinterpret_cast<const bf16x8*>(Wsh + wo);
            bf16x8 bsl = *reinterpret_cast<const bf16x8*>(Wsl + wo);
            bf16x8 bnh = *reinterpret_cast<const bf16x8*>(Wnh + wo);
            bf16x8 bnl = *reinterpret_cast<const bf16x8*>(Wnl + wo);
            acc[ct] = MFMA(a_xh, bsh, acc[ct]);
            acc[ct] = MFMA(a_xh, bsl, acc[ct]);
            acc[ct] = MFMA(a_xl, bsh, acc[ct]);
            acc[ct] = MFMA(a_ah, bnh, acc[ct]);
            acc[ct] = MFMA(a_ah, bnl, acc[ct]);
            acc[ct] = MFMA(a_al, bnh, acc[ct]);
        }
    }
    int dr = (l >> 4) * 4;
#pragma unroll
    for (int j = 0; j < 4; ++j) {
        // row = row0 + w*16 + dr + j ; cols n = ct*16+lr, valid n<40 (ct==2 -> lr<8)
        float v0 = acc[0][j], v1 = acc[1][j];
        float v2 = (lr < 8) ? acc[2][j] : -INFINITY;
        float m = fmaxf(v0, fmaxf(v1, v2));
#pragma unroll
        for (int o = 8; o; o >>= 1) m = fmaxf(m, __shfl_xor(m, o, 16));
        float e = expf(v0 - m) + expf(v1 - m) + ((lr < 8) ? expf(v2 - m) : 0.f);
#pragma unroll
        for (int o = 8; o; o >>= 1) e += __shfl_xor(e, o, 16);
        float lse = m + logf(e);
        int row = row0 + w * 16 + dr + j;
        if (row < NODES) {
            out[(size_t)row * DOUT + lr] = v0 - lse;
            out[(size_t)row * DOUT + 16 + lr] = v1 - lse;
            if (lr < 8) out[(size_t)row * DOUT + 32 + lr] = acc[2][j] - lse;
        }
    }
}

// ================= batchnorm =================

__global__ __launch_bounds__(256) void bn_stats_kernel(const float* __restrict__ h,
                                                       float* __restrict__ sums,
                                                       float* __restrict__ sumsq) {
    int j = threadIdx.x & 127;
    int half = threadIdx.x >> 7;
    float s = 0.f, q = 0.f;
    for (int i = blockIdx.x * 2 + half; i < NODES; i += gridDim.x * 2) {
        float v = h[(size_t)i * 128 + j];
        s += v; q += v * v;
    }
    __shared__ float ls[256], lq[256];
    ls[threadIdx.x] = s; lq[threadIdx.x] = q;
    __syncthreads();
    if (half == 0) {
        atomicAdd(&sums[j], s + ls[threadIdx.x + 128]);
        atomicAdd(&sumsq[j], q + lq[threadIdx.x + 128]);
    }
}

// fused finalize+apply+relu: writes f32 (for GEMM) and bf16 (for gather)
__global__ void bn_apply_kernel(float* __restrict__ h, ushort* __restrict__ hb,
                                const float* __restrict__ sums, const float* __restrict__ sumsq,
                                const float* __restrict__ gamma, const float* __restrict__ beta) {
    long long t = (long long)blockIdx.x * blockDim.x + threadIdx.x;
    if (t >= (long long)NODES * 32) return;
    int j4 = ((int)(t & 31)) * 4;
    size_t off = (size_t)(t >> 5) * 128 + j4;
    float4 v = *reinterpret_cast<float4*>(h + off);
    float4 s4 = *reinterpret_cast<const float4*>(sums + j4);
    float4 q4 = *reinterpret_cast<const float4*>(sumsq + j4);
    float4 g4 = *reinterpret_cast<const float4*>(gamma + j4);
    float4 be4 = *reinterpret_cast<const float4*>(beta + j4);
    const float inv = 1.0f / NODES;
    float m, var, a;
    m = s4.x * inv; var = q4.x * inv - m * m; a = g4.x * rsqrtf(var + 1e-5f);
    v.x = fmaxf(v.x * a + (be4.x - m * a), 0.f);
    m = s4.y * inv; var = q4.y * inv - m * m; a = g4.y * rsqrtf(var + 1e-5f);
    v.y = fmaxf(v.y * a + (be4.y - m * a), 0.f);
    m = s4.z * inv; var = q4.z * inv - m * m; a = g4.z * rsqrtf(var + 1e-5f);
    v.z = fmaxf(v.z * a + (be4.z - m * a), 0.f);
    m = s4.w * inv; var = q4.w * inv - m * m; a = g4.w * rsqrtf(var + 1e-5f);
    v.w = fmaxf(v.w * a + (be4.w - m * a), 0.f);
    *reinterpret_cast<float4*>(h + off) = v;
    ushort4 o;
    o.x = bfh(v.x); o.y = bfh(v.y); o.z = bfh(v.z); o.w = bfh(v.w);
    *reinterpret_cast<ushort4*>(hb + off) = o;
}

extern "C" void kernel_launch(void* const* d_in, const int* in_sizes, int n_in,
                              void* d_out, int out_size, void* d_ws, size_t ws_size,
                              hipStream_t stream) {
    const float* feat   = (const float*)d_in[0];
    const float* Ws1    = (const float*)d_in[1];
    const float* Wn1    = (const float*)d_in[2];
    const float* gamma1 = (const float*)d_in[3];
    const float* beta1  = (const float*)d_in[4];
    const float* Ws2    = (const float*)d_in[5];
    const float* Wn2    = (const float*)d_in[6];
    const float* gamma2 = (const float*)d_in[7];
    const float* beta2  = (const float*)d_in[8];
    const float* Ws3    = (const float*)d_in[9];
    const float* Wn3    = (const float*)d_in[10];
    const int*   src    = (const int*)d_in[11];
    const int*   dst    = (const int*)d_in[12];
    float* out = (float*)d_out;

    float* ws = (float*)d_ws;
    const size_t NF = (size_t)NODES * 128;
    float* xbuf = ws;                       // N*128 f32
    float* agg  = ws + NF;                  // N*128 f32 (aliased as ebuf during CSR build)
    float* sums  = ws + 2 * NF;             // 128 (stat0 = sums, 256 floats contiguous)
    float* sumsq = sums + 128;
    ushort* xb   = (ushort*)(sumsq + 128);  // N*128 bf16 (gather input)
    ushort* Wh   = xb + NF;                 // combined hi: 4*16384 + 2*6144 = 77824
    ushort* Wl   = Wh + 77824;
    int* rowptr = (int*)(Wl + 77824);       // N+1
    uint* ghist = (uint*)(rowptr + NODES + 1);  // GH
    uint* hpart = ghist + GH;               // 128
    uint* hpoff = hpart + 128;              // 128
    int* bucket_base = (int*)(hpoff + 128); // NBUCK+1
    int* col    = bucket_base + NBUCK + 1;  // E
    uint2* ebuf = (uint2*)agg;              // E uint2, dead before gather

    // weight sub-pointers inside combined split buffers
    ushort* Wsh1 = Wh;           ushort* Wsl1 = Wl;
    ushort* Wnh1 = Wh + 16384;   ushort* Wnl1 = Wl + 16384;
    ushort* Wsh2 = Wh + 32768;   ushort* Wsl2 = Wl + 32768;
    ushort* Wnh2 = Wh + 49152;   ushort* Wnl2 = Wl + 49152;
    ushort* Wsh3 = Wh + 65536;   ushort* Wsl3 = Wl + 65536;
    ushort* Wnh3 = Wh + 71680;   ushort* Wnl3 = Wl + 71680;

    const int GEMM_GRID  = NODES / 32;           // 3125
    const int GEMM3_GRID = (NODES + 63) / 64;    // 1563
    const int AGG_GRID   = NODES / 4;            // 25000

    // ---- CSR build: bucket sort, LDS atomics only ----
    hist1_kernel<<<HB, 256, 0, stream>>>(dst, ghist);
    hs1_kernel<<<NHS, 512, 0, stream>>>(ghist, hpart);
    hs2_kernel<<<1, 128, 0, stream>>>(hpart, hpoff, rowptr, bucket_base);
    hs3_kernel<<<NHS, 512, 0, stream>>>(ghist, hpoff, bucket_base);
    scatter1_kernel<<<HB, 256, 0, stream>>>(src, dst, ghist, ebuf);
    csr2_kernel<<<NBUCK, 256, 0, stream>>>(ebuf, bucket_base, rowptr, col);

    // ---- weight splits (1 dispatch) + feat bf16 copy ----
    wsplit_all_kernel<<<304, 256, 0, stream>>>(Ws1, Wn1, Ws2, Wn2, Ws3, Wn3, Wh, Wl);
    f2b_kernel<<<(int)(NF / 4 / 256), 256, 0, stream>>>(feat, xb);

    // ---- layer 1 ----
    gather_agg_kernel<<<AGG_GRID, 256, 0, stream>>>(xb, rowptr, col, agg);
    gemm12_kernel<<<GEMM_GRID, 256, 0, stream>>>(feat, agg, Wsh1, Wsl1, Wnh1, Wnl1, xbuf, sums);
    bn_stats_kernel<<<1024, 256, 0, stream>>>(xbuf, sums, sumsq);
    bn_apply_kernel<<<(NODES * 32) / 256, 256, 0, stream>>>(xbuf, xb, sums, sumsq, gamma1, beta1);

    // ---- layer 2 (GEMM in-place: rows are block-private) ----
    gather_agg_kernel<<<AGG_GRID, 256, 0, stream>>>(xb, rowptr, col, agg);
    gemm12_kernel<<<GEMM_GRID, 256, 0, stream>>>(xbuf, agg, Wsh2, Wsl2, Wnh2, Wnl2, xbuf, sums);
    bn_stats_kernel<<<1024, 256, 0, stream>>>(xbuf, sums, sumsq);
    bn_apply_kernel<<<(NODES * 32) / 256, 256, 0, stream>>>(xbuf, xb, sums, sumsq, gamma2, beta2);

    // ---- layer 3 (+fused log-softmax) ----
    gather_agg_kernel<<<AGG_GRID, 256, 0, stream>>>(xb, rowptr, col, agg);
    gemm3_kernel<<<GEMM3_GRID, 256, 0, stream>>>(xbuf, agg, Wsh3, Wsl3, Wnh3, Wnl3, out);
}